// Round 17
// baseline (1015.959 us; speedup 1.0000x reference)
//
#include <hip/hip_runtime.h>
#include <hip/hip_bf16.h>
#include <cstdint>

#define N_NODES 50000
#define M_SRC   1024
#define E_EDGES 200000
#define EMB     256
#define HIDN    512
#define VOCABSZ 512
#define KW      1280   // wide GEMM K = 256 (h) + 1024 (Bagg)

typedef __attribute__((ext_vector_type(8))) short bf16x8;
typedef __attribute__((ext_vector_type(4))) short bf16x4;
typedef __attribute__((ext_vector_type(4))) float f32x4;

__device__ inline short f2b(float f) {
    __hip_bfloat16 b = __float2bfloat16(f);
    return *reinterpret_cast<short*>(&b);
}
__device__ inline float b2f(short s) {
    __hip_bfloat16 b = *reinterpret_cast<__hip_bfloat16*>(&s);
    return __bfloat162float(b);
}

// async global->LDS, 16B per lane. LDS dest = wave-uniform base + lane*16.
__device__ inline void gload16(const void* g, void* l) {
    __builtin_amdgcn_global_load_lds(
        (const __attribute__((address_space(1))) unsigned int*)g,
        (__attribute__((address_space(3))) unsigned int*)l,
        16, 0, 0);
}

// hardware transpose-read pair (earlyclobber: outputs must not alias addr reg)
__device__ inline void tr_read2(unsigned addr, bf16x4& lo, bf16x4& hi) {
    asm volatile("ds_read_b64_tr_b16 %0, %2\n\tds_read_b64_tr_b16 %1, %2 offset:512"
                 : "=&v"(lo), "=&v"(hi) : "v"(addr));
}

// ---------------------------------------------------------------- embedding -> bf16
__global__ void embed_kernel(const int* __restrict__ tgt_x,
                             const float* __restrict__ table,
                             short* __restrict__ h)
{
    int n = blockIdx.x, d = threadIdx.x;
    const int* tx = tgt_x + (size_t)n * 3;
    float s = table[(size_t)tx[0] * EMB + d]
            + table[(size_t)tx[1] * EMB + d]
            + table[(size_t)tx[2] * EMB + d];
    h[(size_t)n * EMB + d] = f2b(s);
}

// ---------------------------------------------------------------- fp32 -> bf16 flat convert
__global__ void convert_kernel(const float* __restrict__ in, short* __restrict__ out, int n)
{
    int i = blockIdx.x * 256 + threadIdx.x;
    if (i * 4 < n) {
        float4 v = *(const float4*)&in[i * 4];
        short4 o;
        o.x = f2b(v.x); o.y = f2b(v.y); o.z = f2b(v.z); o.w = f2b(v.w);
        *(short4*)&out[i * 4] = o;
    }
}

// ---------------------------------------------------------------- transpose to bf16
template<typename TIN>
__global__ void transpose_kernel(const TIN* __restrict__ in, short* __restrict__ out, int R, int C)
{
    __shared__ float t[32][33];
    int tx = threadIdx.x & 31, ty = threadIdx.x >> 5;   // 32 x 8
    int r0 = blockIdx.y * 32, c0 = blockIdx.x * 32;
#pragma unroll
    for (int i = 0; i < 4; i++) {
        int r = ty + i * 8;
        TIN v = in[(size_t)(r0 + r) * C + c0 + tx];
        if constexpr (sizeof(TIN) == 4) t[r][tx] = v;
        else                            t[r][tx] = b2f(v);
    }
    __syncthreads();
#pragma unroll
    for (int i = 0; i < 4; i++) {
        int r = ty + i * 8;
        out[(size_t)(c0 + r) * R + r0 + tx] = f2b(t[tx][r]);
    }
}

// ---------------------------------------------------------------- weight transposes -> Wcat [256][1280]
__global__ void transposeW_kernel(const float* __restrict__ Wh1, const float* __restrict__ Wh3,
                                  const float* __restrict__ Wr1, const float* __restrict__ Wr3,
                                  short* __restrict__ Wcat1, short* __restrict__ Wcat3)
{
    __shared__ float t[32][33];
    const int z = blockIdx.z;
    const float* in; short* outp; int coloff;
    if (z == 0)      { in = Wh1;                               outp = Wcat1; coloff = 0; }
    else if (z == 1) { in = Wh3;                               outp = Wcat3; coloff = 0; }
    else if (z < 6)  { in = Wr1 + (size_t)(z - 2) * EMB * EMB; outp = Wcat1; coloff = 256 + (z - 2) * 256; }
    else             { in = Wr3 + (size_t)(z - 6) * EMB * EMB; outp = Wcat3; coloff = 256 + (z - 6) * 256; }
    int tx = threadIdx.x & 31, ty = threadIdx.x >> 5;
    int r0 = blockIdx.y * 32, c0 = blockIdx.x * 32;
#pragma unroll
    for (int i = 0; i < 4; i++) {
        int r = ty + i * 8;
        t[r][tx] = in[(size_t)(r0 + r) * EMB + c0 + tx];
    }
    __syncthreads();
#pragma unroll
    for (int i = 0; i < 4; i++) {
        int r = ty + i * 8;
        outp[(size_t)(c0 + r) * KW + coloff + r0 + tx] = f2b(t[tx][r]);
    }
}

// ---------------------------------------------------------------- MFMA GEMM (r8-proven, MODE 0 only)
template<int MODE>
__global__ __launch_bounds__(256) void mgemm(
    const short* __restrict__ A, const short* __restrict__ BT,
    void* __restrict__ outp, const float* __restrict__ aux,
    const float* __restrict__ bias, int NR, int K, int J)
{
    __shared__ short As[128 * 40];
    __shared__ short Bs[128 * 40];
    const int tid  = threadIdx.x;
    const int n0   = blockIdx.x * 128;
    const int j0   = blockIdx.y * 128;
    const int lane = tid & 63, wid = tid >> 6;
    const int wr   = wid >> 1, wc = wid & 1;

    f32x4 acc[4][4];
#pragma unroll
    for (int m = 0; m < 4; m++)
#pragma unroll
        for (int n = 0; n < 4; n++) acc[m][n] = (f32x4){0.f, 0.f, 0.f, 0.f};

    for (int kt = 0; kt < K; kt += 32) {
#pragma unroll
        for (int r = 0; r < 2; r++) {
            int idx = tid + r * 256;
            int row = idx >> 2, ko = (idx & 3) * 8;
            int n = n0 + row;
            bf16x8 av = {0, 0, 0, 0, 0, 0, 0, 0};
            if (n < NR) av = *(const bf16x8*)&A[(size_t)n * K + kt + ko];
            *(bf16x8*)&As[row * 40 + ko] = av;
            *(bf16x8*)&Bs[row * 40 + ko] = *(const bf16x8*)&BT[(size_t)(j0 + row) * K + kt + ko];
        }
        __syncthreads();
        bf16x8 af[4], bfr[4];
#pragma unroll
        for (int m = 0; m < 4; m++)
            af[m] = *(const bf16x8*)&As[(wr * 64 + m * 16 + (lane & 15)) * 40 + (lane >> 4) * 8];
#pragma unroll
        for (int n = 0; n < 4; n++)
            bfr[n] = *(const bf16x8*)&Bs[(wc * 64 + n * 16 + (lane & 15)) * 40 + (lane >> 4) * 8];
#pragma unroll
        for (int m = 0; m < 4; m++)
#pragma unroll
            for (int n = 0; n < 4; n++)
                acc[m][n] = __builtin_amdgcn_mfma_f32_16x16x32_bf16(af[m], bfr[n], acc[m][n], 0, 0, 0);
        __syncthreads();
    }

#pragma unroll
    for (int m = 0; m < 4; m++) {
        int rbase = wr * 64 + m * 16 + ((lane >> 4) * 4);
#pragma unroll
        for (int r = 0; r < 4; r++) {
            int n_g = n0 + rbase + r;
            if (n_g >= NR) continue;
#pragma unroll
            for (int nn = 0; nn < 4; nn++) {
                int j_g = j0 + wc * 64 + nn * 16 + (lane & 15);
                ((short*)outp)[(size_t)n_g * J + j_g] = f2b(acc[m][nn][r]);
            }
        }
    }
}

// ---------------------------------------------------------------- wide GEMM v4 (aux in bf16)
// h_nxt = relu([h|Bagg] @ Wcat^T + C).  BM=64 x BN=256, BK=64, grid 782.
__global__ __launch_bounds__(256) void mgemm_wide(
    const short* __restrict__ A1, const short* __restrict__ A2,
    const short* __restrict__ BT, short* __restrict__ outp,
    const short* __restrict__ aux, int NR)
{
    __shared__ short As[2][4096];    // 2 subtiles (32x64) x dbuf = 16 KB
    __shared__ short Bs[2][16384];   // 8 subtiles x dbuf = 64 KB
    const int tid  = threadIdx.x;
    const int n0   = blockIdx.x * 64;
    const int lane = tid & 63, wid = tid >> 6;
    const int wr   = wid >> 1, wc = wid & 1;
    const int l4 = lane >> 4, l15 = lane & 15;

    auto SOFF = [](int r, int d8) {
        return (d8 & 1) * 8 + (r & 3) * 16 + ((r >> 3) & 3) * 64
             + ((r >> 2) & 1) * 256 + (d8 >> 1) * 512;
    };
    int a_row[2], a_d8[2];
#pragma unroll
    for (int q = 0; q < 2; q++) {
        int cig = tid + q * 256;
        int s = cig >> 8, ci = cig & 255;
        a_d8[q]  = (ci & 1) | (((ci >> 6) & 3) << 1);
        a_row[q] = s * 32 + (((ci >> 1) & 3) | (((ci >> 5) & 1) << 2) | (((ci >> 3) & 3) << 3));
    }
    int b_row[8], b_d8[8];
#pragma unroll
    for (int q = 0; q < 8; q++) {
        int cig = tid + q * 256;
        int s = cig >> 8, ci = cig & 255;
        b_d8[q]  = (ci & 1) | (((ci >> 6) & 3) << 1);
        b_row[q] = s * 32 + (((ci >> 1) & 3) | (((ci >> 5) & 1) << 2) | (((ci >> 3) & 3) << 3));
    }

    f32x4 acc[2][8];
#pragma unroll
    for (int m = 0; m < 2; m++)
#pragma unroll
        for (int n = 0; n < 8; n++) acc[m][n] = (f32x4){0.f, 0.f, 0.f, 0.f};

    auto STAGE = [&](int buf, int kt) {
#pragma unroll
        for (int q = 0; q < 2; q++) {
            int col = kt + a_d8[q] * 8;
            const short* src = (col < 256) ? &A1[(size_t)(n0 + a_row[q]) * 256 + col]
                                           : &A2[(size_t)(n0 + a_row[q]) * 1024 + (col - 256)];
            gload16(src, (char*)&As[buf][0] + q * 4096 + wid * 1024);
        }
#pragma unroll
        for (int q = 0; q < 8; q++) {
            gload16(&BT[(size_t)b_row[q] * KW + kt + b_d8[q] * 8],
                    (char*)&Bs[buf][0] + q * 4096 + wid * 1024);
        }
    };

    STAGE(0, 0);
    __syncthreads();

    for (int t = 0; t < 20; t++) {
        const int cur = t & 1;
        if (t + 1 < 20) STAGE(cur ^ 1, (t + 1) * 64);
#pragma unroll
        for (int kst = 0; kst < 2; kst++) {
            const int d8 = kst * 4 + l4;
            bf16x8 af[2], bfr[8];
#pragma unroll
            for (int m = 0; m < 2; m++)
                af[m] = *(const bf16x8*)&As[cur][wr * 2048 + SOFF(m * 16 + l15, d8)];
#pragma unroll
            for (int n = 0; n < 8; n++) {
                int sb = wc * 4 + (n >> 1);
                int r  = (n & 1) * 16 + l15;
                bfr[n] = *(const bf16x8*)&Bs[cur][sb * 2048 + SOFF(r, d8)];
            }
            __builtin_amdgcn_s_setprio(1);
#pragma unroll
            for (int m = 0; m < 2; m++)
#pragma unroll
                for (int n = 0; n < 8; n++)
                    acc[m][n] = __builtin_amdgcn_mfma_f32_16x16x32_bf16(af[m], bfr[n], acc[m][n], 0, 0, 0);
            __builtin_amdgcn_s_setprio(0);
        }
        __syncthreads();   // drains gload_lds for buf cur^1 + orders buffer reuse
    }

#pragma unroll
    for (int m = 0; m < 2; m++) {
        int rbase = wr * 32 + m * 16 + l4 * 4;
#pragma unroll
        for (int r = 0; r < 4; r++) {
            int n_g = n0 + rbase + r;
            if (n_g >= NR) continue;
#pragma unroll
            for (int nn = 0; nn < 8; nn++) {
                int j_g = wc * 128 + nn * 16 + l15;
                float v = acc[m][nn][r] + b2f(aux[(size_t)n_g * 256 + j_g]);
                outp[(size_t)n_g * 256 + j_g] = f2b(fmaxf(v, 0.f));
            }
        }
    }
}

// ---------------------------------------------------------------- fused flash attention v8
// 3-buffer rotation, prefetch distance 2, counted vmcnt(8) + raw s_barrier
// (prefetch loads never drained by their own chunk's barrier).
__global__ __launch_bounds__(128, 2) void attn_flash(
    const short* __restrict__ h, const short* __restrict__ kb,
    short* __restrict__ C, int NR)
{
    __shared__ short ks[3][32 * 256];   // 3 x 16 KB, subtiled layout
    __shared__ short Ps[64 * 36];       // wave-private rows, pad-36

    const int tid = threadIdx.x;
    const int lane = tid & 63, wv = tid >> 6;   // wv 0..1
    const int l4 = lane >> 4, l15 = lane & 15;
    const int n0 = blockIdx.x * 64;

    auto LOFF = [](int key, int d8) {
        return (d8 & 1) * 8 + (key & 3) * 16 + ((key >> 3) & 3) * 64
             + ((key >> 2) & 1) * 256 + (d8 >> 1) * 512;
    };
    int keyq[8], d8q[8];
#pragma unroll
    for (int q = 0; q < 8; q++) {
        int ci = wv * 64 + lane + q * 128;
        d8q[q]  = (ci & 1) | ((ci >> 6) << 1);
        keyq[q] = ((ci >> 1) & 3) | (((ci >> 5) & 1) << 2) | (((ci >> 3) & 3) << 3);
    }

    bf16x8 hreg[2][8];
#pragma unroll
    for (int rg = 0; rg < 2; rg++) {
        int n = n0 + wv * 32 + rg * 16 + l15;
        const short* hp = &h[(size_t)(n < NR ? n : 0) * 256 + l4 * 8];
#pragma unroll
        for (int kst = 0; kst < 8; kst++) hreg[rg][kst] = *(const bf16x8*)&hp[kst * 32];
        if (n >= NR) {
#pragma unroll
            for (int kst = 0; kst < 8; kst++) hreg[rg][kst] = (bf16x8){0, 0, 0, 0, 0, 0, 0, 0};
        }
    }

    // prologue: stage chunks 0 and 1
#pragma unroll
    for (int q = 0; q < 8; q++)
        gload16(&kb[(size_t)keyq[q] * 256 + d8q[q] * 8],
                (char*)&ks[0][0] + q * 2048 + wv * 1024);
    {
        const short* kb1 = kb + (size_t)32 * 256;
#pragma unroll
        for (int q = 0; q < 8; q++)
            gload16(&kb1[(size_t)keyq[q] * 256 + d8q[q] * 8],
                    (char*)&ks[1][0] + q * 2048 + wv * 1024);
    }
    __syncthreads();   // full drain once (chunks 0 and 1 both resident)

    const unsigned ksbase = (unsigned)(uintptr_t)&ks[0][0];
    const unsigned trlane = 2u * (unsigned)(l15 + l4 * 64);

    f32x4 oacc[2][16];
#pragma unroll
    for (int rg = 0; rg < 2; rg++)
#pragma unroll
        for (int mm = 0; mm < 16; mm++) oacc[rg][mm] = (f32x4){0.f, 0.f, 0.f, 0.f};
    float lsum[2] = {0.f, 0.f};

    int cur = 0;
    for (int c = 0; c < 32; c++) {
        // prefetch distance 2 into the buffer freed at the previous barrier
        if (c + 2 < 32) {
            int sb = cur + 2; if (sb >= 3) sb -= 3;
            const short* kbn = kb + (size_t)(c + 2) * 32 * 256;
#pragma unroll
            for (int q = 0; q < 8; q++)
                gload16(&kbn[(size_t)keyq[q] * 256 + d8q[q] * 8],
                        (char*)&ks[sb][0] + q * 2048 + wv * 1024);
        }

        f32x4 sacc[2][2];
#pragma unroll
        for (int rg = 0; rg < 2; rg++) {
            sacc[rg][0] = (f32x4){0.f, 0.f, 0.f, 0.f};
            sacc[rg][1] = (f32x4){0.f, 0.f, 0.f, 0.f};
        }
        __builtin_amdgcn_s_setprio(1);
#pragma unroll
        for (int kst = 0; kst < 8; kst++) {
#pragma unroll
            for (int m = 0; m < 2; m++) {
                int krow = m * 16 + l15;
                bf16x8 afk = *(const bf16x8*)&ks[cur][LOFF(krow, kst * 4 + l4)];
                sacc[0][m] = __builtin_amdgcn_mfma_f32_16x16x32_bf16(afk, hreg[0][kst], sacc[0][m], 0, 0, 0);
                sacc[1][m] = __builtin_amdgcn_mfma_f32_16x16x32_bf16(afk, hreg[1][kst], sacc[1][m], 0, 0, 0);
            }
        }
        __builtin_amdgcn_s_setprio(0);

#pragma unroll
        for (int rg = 0; rg < 2; rg++) {
            int prow = wv * 32 + rg * 16 + l15;
            float psum = 0.f;
#pragma unroll
            for (int m = 0; m < 2; m++) {
                float p0 = __expf(sacc[rg][m][0] * 0.0625f);
                float p1 = __expf(sacc[rg][m][1] * 0.0625f);
                float p2 = __expf(sacc[rg][m][2] * 0.0625f);
                float p3 = __expf(sacc[rg][m][3] * 0.0625f);
                psum += (p0 + p1) + (p2 + p3);
                short4 pk;
                pk.x = f2b(p0); pk.y = f2b(p1); pk.z = f2b(p2); pk.w = f2b(p3);
                *(short4*)&Ps[prow * 36 + m * 16 + l4 * 4] = pk;
            }
            psum += __shfl_xor(psum, 16);
            psum += __shfl_xor(psum, 32);
            lsum[rg] += psum;
        }

        bf16x8 bf2[2];
#pragma unroll
        for (int rg = 0; rg < 2; rg++)
            bf2[rg] = *(const bf16x8*)&Ps[(wv * 32 + rg * 16 + l15) * 36 + l4 * 8];
        unsigned trb = ksbase + (unsigned)(cur * 16384) + trlane;
#pragma unroll
        for (int g = 0; g < 2; g++) {
            bf16x4 lo[8], hi[8];
#pragma unroll
            for (int q = 0; q < 8; q++)
                tr_read2(trb + (unsigned)((g * 8 + q) * 1024), lo[q], hi[q]);
            asm volatile("s_waitcnt lgkmcnt(0)" ::: "memory");
            __builtin_amdgcn_sched_barrier(0);
            __builtin_amdgcn_s_setprio(1);
#pragma unroll
            for (int q = 0; q < 8; q++) {
                bf16x8 af2;
#pragma unroll
                for (int t2 = 0; t2 < 4; t2++) { af2[t2] = lo[q][t2]; af2[t2 + 4] = hi[q][t2]; }
                oacc[0][g * 8 + q] = __builtin_amdgcn_mfma_f32_16x16x32_bf16(af2, bf2[0], oacc[0][g * 8 + q], 0, 0, 0);
                oacc[1][g * 8 + q] = __builtin_amdgcn_mfma_f32_16x16x32_bf16(af2, bf2[1], oacc[1][g * 8 + q], 0, 0, 0);
            }
            __builtin_amdgcn_s_setprio(0);
        }

        // counted drain: wait only for chunk c+1's loads (issued one chunk ago);
        // the 8 just-issued (c+2) stay in flight across the raw barrier.
        if (c + 2 < 32) {
            asm volatile("s_waitcnt vmcnt(8)" ::: "memory");
        } else {
            asm volatile("s_waitcnt vmcnt(0)" ::: "memory");
        }
        __builtin_amdgcn_sched_barrier(0);
        __builtin_amdgcn_s_barrier();
        __builtin_amdgcn_sched_barrier(0);

        cur = (cur + 1 == 3) ? 0 : cur + 1;
    }

#pragma unroll
    for (int rg = 0; rg < 2; rg++) {
        float li = 1.0f / lsum[rg];
        int hr = n0 + wv * 32 + rg * 16 + l15;
        if (hr >= NR) continue;
#pragma unroll
        for (int mm = 0; mm < 16; mm++) {
            short4 o;
            o.x = f2b(oacc[rg][mm][0] * li);
            o.y = f2b(oacc[rg][mm][1] * li);
            o.z = f2b(oacc[rg][mm][2] * li);
            o.w = f2b(oacc[rg][mm][3] * li);
            *(short4*)&C[(size_t)hr * 256 + mm * 16 + l4 * 4] = o;
        }
    }
}

// ---------------------------------------------------------------- CSR build (once per call)
__global__ void hist_kernel(const int* __restrict__ ei, int* __restrict__ deg)
{
    int e = blockIdx.x * 256 + threadIdx.x;
    if (e < E_EDGES) atomicAdd(&deg[ei[E_EDGES + e]], 1);
}

__global__ void scan1_kernel(const int* __restrict__ deg, int* __restrict__ incl,
                             int* __restrict__ bsum)
{
    __shared__ int s[256];
    int i = blockIdx.x * 256 + threadIdx.x;
    int v = (i < N_NODES) ? deg[i] : 0;
    s[threadIdx.x] = v;
    __syncthreads();
#pragma unroll
    for (int off = 1; off < 256; off <<= 1) {
        int t = (threadIdx.x >= off) ? s[threadIdx.x - off] : 0;
        __syncthreads();
        s[threadIdx.x] += t;
        __syncthreads();
    }
    if (i < N_NODES) incl[i] = s[threadIdx.x];
    if (threadIdx.x == 255) bsum[blockIdx.x] = s[255];
}

__global__ void scan2_kernel(int* __restrict__ bsum, int nb)
{
    __shared__ int s[256];
    int v = (threadIdx.x < nb) ? bsum[threadIdx.x] : 0;
    s[threadIdx.x] = v;
    __syncthreads();
#pragma unroll
    for (int off = 1; off < 256; off <<= 1) {
        int t = (threadIdx.x >= off) ? s[threadIdx.x - off] : 0;
        __syncthreads();
        s[threadIdx.x] += t;
        __syncthreads();
    }
    if (threadIdx.x < nb) bsum[threadIdx.x] = s[threadIdx.x];
}

__global__ void scan3_kernel(const int* __restrict__ deg, const int* __restrict__ incl,
                             const int* __restrict__ bsum, int* __restrict__ row_ptr,
                             int* __restrict__ cursor)
{
    int i = blockIdx.x * 256 + threadIdx.x;
    if (i >= N_NODES) return;
    int pref = (blockIdx.x > 0) ? bsum[blockIdx.x - 1] : 0;
    int start = pref + incl[i] - deg[i];
    row_ptr[i] = start;
    cursor[i]  = start;
    if (i == N_NODES - 1) row_ptr[N_NODES] = pref + incl[i];
}

__global__ void fill_kernel(const int* __restrict__ ei, const int* __restrict__ et,
                            int* __restrict__ cursor, int* __restrict__ eidx)
{
    int e = blockIdx.x * 256 + threadIdx.x;
    if (e >= E_EDGES) return;
    int tg = ei[E_EDGES + e];
    int slot = atomicAdd(&cursor[tg], 1);
    eidx[slot] = ei[e] | (et[e] << 16);   // src < 65536, type < 4
}

// ---------------------------------------------------------------- CSR gather of h into per-type buckets
__global__ void agg2_kernel(const int* __restrict__ row_ptr, const int* __restrict__ eidx,
                            const short* __restrict__ h, short* __restrict__ Bagg)
{
    int w = (blockIdx.x * 256 + threadIdx.x) >> 6;
    if (w >= N_NODES) return;
    int lane = threadIdx.x & 63;
    int s0 = row_ptr[w], s1 = row_ptr[w + 1];
    float a0[4] = {0, 0, 0, 0}, a1[4] = {0, 0, 0, 0}, a2[4] = {0, 0, 0, 0}, a3[4] = {0, 0, 0, 0};
    for (int i = s0; i < s1; i++) {
        int p = eidx[i];
        int s = p & 0xFFFF, t = p >> 16;   // t uniform across the wave
        short4 g = *(const short4*)&h[(size_t)s * EMB + lane * 4];
        float f0 = b2f(g.x), f1 = b2f(g.y), f2 = b2f(g.z), f3 = b2f(g.w);
        if (t == 0)      { a0[0] += f0; a0[1] += f1; a0[2] += f2; a0[3] += f3; }
        else if (t == 1) { a1[0] += f0; a1[1] += f1; a1[2] += f2; a1[3] += f3; }
        else if (t == 2) { a2[0] += f0; a2[1] += f1; a2[2] += f2; a2[3] += f3; }
        else             { a3[0] += f0; a3[1] += f1; a3[2] += f2; a3[3] += f3; }
    }
    short4 o;
    o.x = f2b(a0[0]); o.y = f2b(a0[1]); o.z = f2b(a0[2]); o.w = f2b(a0[3]);
    *(short4*)&Bagg[(size_t)w * 1024 + 0 * 256 + lane * 4] = o;
    o.x = f2b(a1[0]); o.y = f2b(a1[1]); o.z = f2b(a1[2]); o.w = f2b(a1[3]);
    *(short4*)&Bagg[(size_t)w * 1024 + 1 * 256 + lane * 4] = o;
    o.x = f2b(a2[0]); o.y = f2b(a2[1]); o.z = f2b(a2[2]); o.w = f2b(a2[3]);
    *(short4*)&Bagg[(size_t)w * 1024 + 2 * 256 + lane * 4] = o;
    o.x = f2b(a3[0]); o.y = f2b(a3[1]); o.z = f2b(a3[2]); o.w = f2b(a3[3]);
    *(short4*)&Bagg[(size_t)w * 1024 + 3 * 256 + lane * 4] = o;
}

// ---------------------------------------------------------------- fused node head
__global__ __launch_bounds__(512, 2) void head_kernel(
    const short* __restrict__ hmat, const short* __restrict__ WzT,
    const float* __restrict__ bz, float* __restrict__ out, int NR)
{
    __shared__ short hs[64 * 256];   // swizzled
    __shared__ float redm[64 * 8];
    __shared__ float reds[64 * 8];

    const int tid = threadIdx.x;
    const int lane = tid & 63, wv = tid >> 6;  // wv 0..7
    const int l4 = lane >> 4, l15 = lane & 15;
    const int n0 = blockIdx.x * 64;

#pragma unroll
    for (int i = 0; i < 4; i++) {
        int idx = tid + i * 512;
        int row = idx >> 5, kg = idx & 31;
        bf16x8 v = {0, 0, 0, 0, 0, 0, 0, 0};
        if (n0 + row < NR) v = *(const bf16x8*)&hmat[(size_t)(n0 + row) * 256 + kg * 8];
        *(bf16x8*)&hs[(row * 256 + kg * 8) ^ ((row & 7) << 3)] = v;
    }
    __syncthreads();

    f32x4 acc[4][4];
#pragma unroll
    for (int m = 0; m < 4; m++)
#pragma unroll
        for (int n = 0; n < 4; n++) acc[m][n] = (f32x4){0.f, 0.f, 0.f, 0.f};

#pragma unroll
    for (int kt = 0; kt < 256; kt += 32) {
        bf16x8 af[4], bfr[4];
#pragma unroll
        for (int m = 0; m < 4; m++) {
            int row = m * 16 + l15;
            af[m] = *(const bf16x8*)&hs[(row * 256 + kt + l4 * 8) ^ ((row & 7) << 3)];
        }
#pragma unroll
        for (int n = 0; n < 4; n++) {
            int col = wv * 64 + n * 16 + l15;
            bfr[n] = *(const bf16x8*)&WzT[(size_t)col * 256 + kt + l4 * 8];
        }
#pragma unroll
        for (int m = 0; m < 4; m++)
#pragma unroll
            for (int n = 0; n < 4; n++)
                acc[m][n] = __builtin_amdgcn_mfma_f32_16x16x32_bf16(af[m], bfr[n], acc[m][n], 0, 0, 0);
    }

    float bcol[4];
#pragma unroll
    for (int n = 0; n < 4; n++) bcol[n] = bz[wv * 64 + n * 16 + l15];
#pragma unroll
    for (int m = 0; m < 4; m++)
#pragma unroll
        for (int n = 0; n < 4; n++)
#pragma unroll
            for (int r = 0; r < 4; r++) acc[m][n][r] += bcol[n];

    float lg[4][4];
#pragma unroll
    for (int m = 0; m < 4; m++)
#pragma unroll
        for (int r = 0; r < 4; r++) {
            float v = fmaxf(fmaxf(acc[m][0][r], acc[m][1][r]), fmaxf(acc[m][2][r], acc[m][3][r]));
            v = fmaxf(v, __shfl_xor(v, 1));
            v = fmaxf(v, __shfl_xor(v, 2));
            v = fmaxf(v, __shfl_xor(v, 4));
            v = fmaxf(v, __shfl_xor(v, 8));
            if (l15 == 0) redm[(m * 16 + l4 * 4 + r) * 8 + wv] = v;
        }
    __syncthreads();
#pragma unroll
    for (int m = 0; m < 4; m++)
#pragma unroll
        for (int r = 0; r < 4; r++) {
            int row = m * 16 + l4 * 4 + r;
            float v = redm[row * 8 + 0];
#pragma unroll
            for (int w = 1; w < 8; w++) v = fmaxf(v, redm[row * 8 + w]);
            lg[m][r] = v;
        }
#pragma unroll
    for (int m = 0; m < 4; m++)
#pragma unroll
        for (int r = 0; r < 4; r++) {
            float gm = lg[m][r];
            float s = __expf(acc[m][0][r] - gm) + __expf(acc[m][1][r] - gm)
                    + __expf(acc[m][2][r] - gm) + __expf(acc[m][3][r] - gm);
            s += __shfl_xor(s, 1);
            s += __shfl_xor(s, 2);
            s += __shfl_xor(s, 4);
            s += __shfl_xor(s, 8);
            if (l15 == 0) reds[(m * 16 + l4 * 4 + r) * 8 + wv] = s;
        }
    __syncthreads();
#pragma unroll
    for (int m = 0; m < 4; m++)
#pragma unroll
        for (int r = 0; r < 4; r++) {
            int row = m * 16 + l4 * 4 + r;
            float s = reds[row * 8 + 0];
#pragma unroll
            for (int w = 1; w < 8; w++) s += reds[row * 8 + w];
            lg[m][r] += __logf(s);
        }
#pragma unroll
    for (int m = 0; m < 4; m++)
#pragma unroll
        for (int r = 0; r < 4; r++) {
            int hr = n0 + m * 16 + l4 * 4 + r;
            if (hr >= NR) continue;
#pragma unroll
            for (int n = 0; n < 4; n++)
                out[(size_t)hr * VOCABSZ + wv * 64 + n * 16 + l15] = acc[m][n][r] - lg[m][r];
        }
}

// ---------------------------------------------------------------- node projections for edge head
__global__ __launch_bounds__(256) void nodeproj_kernel(
    const short* __restrict__ h, const float* __restrict__ Wg,
    float* __restrict__ eproj)
{
    int lane = threadIdx.x & 63;
    int gw   = (blockIdx.x * 256 + threadIdx.x) >> 6;
    int nw   = (gridDim.x * 256) >> 6;
    float ws[4][5], wt[4][5];
#pragma unroll
    for (int c = 0; c < 4; c++)
#pragma unroll
        for (int j = 0; j < 5; j++) {
            ws[c][j] = Wg[(size_t)(lane * 4 + c) * 5 + j];
            wt[c][j] = Wg[(size_t)(256 + lane * 4 + c) * 5 + j];
        }

    for (int n = gw; n < N_NODES; n += nw) {
        short4 hv = *(const short4*)&h[(size_t)n * EMB + lane * 4];
        float f[4] = { b2f(hv.x), b2f(hv.y), b2f(hv.z), b2f(hv.w) };
        float a[5] = {0, 0, 0, 0, 0}, b[5] = {0, 0, 0, 0, 0};
#pragma unroll
        for (int c = 0; c < 4; c++)
#pragma unroll
            for (int j = 0; j < 5; j++) {
                a[j] += f[c] * ws[c][j];
                b[j] += f[c] * wt[c][j];
            }
#pragma unroll
        for (int j = 0; j < 5; j++)
#pragma unroll
            for (int off = 32; off; off >>= 1) {
                a[j] += __shfl_xor(a[j], off);
                b[j] += __shfl_xor(b[j], off);
            }
        if (lane == 0) {
#pragma unroll
            for (int j = 0; j < 5; j++) {
                eproj[(size_t)n * 10 + j]     = a[j];
                eproj[(size_t)n * 10 + 5 + j] = b[j];
            }
        }
    }
}

// ---------------------------------------------------------------- edge head combine
__global__ void edge_lsm_kernel(const int* __restrict__ ei,
                                const float* __restrict__ eproj,
                                const float* __restrict__ bg,
                                float* __restrict__ out)
{
    int e = blockIdx.x * 256 + threadIdx.x;
    if (e >= E_EDGES) return;
    int s = ei[e], t = ei[E_EDGES + e];
    const float* ps = &eproj[(size_t)s * 10];
    const float* pt = &eproj[(size_t)t * 10 + 5];
    float z[5];
#pragma unroll
    for (int j = 0; j < 5; j++) z[j] = ps[j] + pt[j] + bg[j];
    float mm = fmaxf(fmaxf(fmaxf(z[0], z[1]), fmaxf(z[2], z[3])), z[4]);
    float ss = __expf(z[0] - mm) + __expf(z[1] - mm) + __expf(z[2] - mm)
             + __expf(z[3] - mm) + __expf(z[4] - mm);
    float lg = mm + __logf(ss);
    float* o = &out[(size_t)e * 5];
#pragma unroll
    for (int j = 0; j < 5; j++) o[j] = z[j] - lg;
}

// ---------------------------------------------------------------- launch
extern "C" void kernel_launch(void* const* d_in, const int* in_sizes, int n_in,
                              void* d_out, int out_size, void* d_ws, size_t ws_size,
                              hipStream_t stream)
{
    const int*   tgt_x = (const int*)  d_in[0];
    const float* x     = (const float*)d_in[1];
    const int*   ei    = (const int*)  d_in[2];
    const int*   et    = (const int*)  d_in[3];
    const float* table = (const float*)d_in[4];
    const float* Wh1   = (const float*)d_in[5];
    const float* Wrel1 = (const float*)d_in[6];
    const float* Wsrc1 = (const float*)d_in[7];
    const float* Wh3   = (const float*)d_in[8];
    const float* Wrel3 = (const float*)d_in[9];
    const float* Wsrc3 = (const float*)d_in[10];
    const float* Wz    = (const float*)d_in[11];
    const float* bz    = (const float*)d_in[12];
    const float* Wg    = (const float*)d_in[13];
    const float* bg    = (const float*)d_in[14];
    float* out = (float*)d_out;

    // ---- workspace layout
    short* h_a = (short*)d_ws;                              // N*256 bf16
    short* h_b = h_a + (size_t)N_NODES * EMB;
    short* C   = h_b + (size_t)N_NODES * EMB;               // N*256 bf16 (ctx)
    short* Bagg = C + (size_t)N_NODES * EMB;                // N*1024 bf16
    short* k1b = Bagg + (size_t)N_NODES * 1024;             // [1024][256]
    short* k3b = k1b + M_SRC * EMB;
    short* x_b = k3b + M_SRC * EMB;                         // [1024][512]
    short* WsT1 = x_b + M_SRC * HIDN;                       // [256][512]
    short* WsT3 = WsT1 + EMB * HIDN;
    short* Wcat1 = WsT3 + EMB * HIDN;                       // [256][1280]
    short* Wcat3 = Wcat1 + EMB * KW;
    short* WzT  = Wcat3 + EMB * KW;                         // [512][256]
    int* deg     = (int*)(WzT + VOCABSZ * EMB);             // N
    int* incl    = deg + N_NODES;                           // N
    int* bsum    = incl + N_NODES;                          // 256
    int* row_ptr = bsum + 256;                              // N+1
    int* cursor  = row_ptr + N_NODES + 1;                   // N
    int* eidx    = cursor + N_NODES;                        // E
    float* eproj = (float*)(eidx + E_EDGES);                // N*10 f32

    const int gN64 = (N_NODES + 63) / 64;                   // 782
    const int nb1 = (N_NODES + 255) / 256;                  // 196

    // ---- CSR build (edges constant across layers)
    hipMemsetAsync(deg, 0, N_NODES * sizeof(int), stream);
    hist_kernel<<<(E_EDGES + 255) / 256, 256, 0, stream>>>(ei, deg);
    scan1_kernel<<<nb1, 256, 0, stream>>>(deg, incl, bsum);
    scan2_kernel<<<1, 256, 0, stream>>>(bsum, nb1);
    scan3_kernel<<<nb1, 256, 0, stream>>>(deg, incl, bsum, row_ptr, cursor);
    fill_kernel<<<(E_EDGES + 255) / 256, 256, 0, stream>>>(ei, et, cursor, eidx);

    // ---- weight prep
    convert_kernel<<<(M_SRC * HIDN / 4 + 255) / 256, 256, 0, stream>>>(x, x_b, M_SRC * HIDN);
    transpose_kernel<float><<<dim3(EMB / 32, HIDN / 32), 256, 0, stream>>>(Wsrc1, WsT1, HIDN, EMB);
    transpose_kernel<float><<<dim3(EMB / 32, HIDN / 32), 256, 0, stream>>>(Wsrc3, WsT3, HIDN, EMB);
    transposeW_kernel<<<dim3(8, 8, 10), 256, 0, stream>>>(Wh1, Wh3, Wrel1, Wrel3, Wcat1, Wcat3);
    transpose_kernel<float><<<dim3(VOCABSZ / 32, EMB / 32), 256, 0, stream>>>(Wz, WzT, EMB, VOCABSZ);

    // ---- k = x @ Wsrc (bf16)
    mgemm<0><<<dim3(M_SRC / 128, EMB / 128), 256, 0, stream>>>(x_b, WsT1, k1b, nullptr, nullptr, M_SRC, HIDN, EMB);
    mgemm<0><<<dim3(M_SRC / 128, EMB / 128), 256, 0, stream>>>(x_b, WsT3, k3b, nullptr, nullptr, M_SRC, HIDN, EMB);

    // ---- embedding
    embed_kernel<<<N_NODES, 256, 0, stream>>>(tgt_x, table, h_a);

    short* h_cur = h_a;
    short* h_nxt = h_b;
    for (int layer = 0; layer < 3; layer++) {
        const short* kb   = (layer < 2) ? k1b   : k3b;
        const short* Wcat = (layer < 2) ? Wcat1 : Wcat3;

        // C = softmax(h k^T / 16) @ k   (fused flash v8, counted-vmcnt pipeline)
        attn_flash<<<gN64, 128, 0, stream>>>(h_cur, kb, C, N_NODES);
        // Bagg[tgt] = per-type sums of h[src]
        agg2_kernel<<<(N_NODES + 3) / 4, 256, 0, stream>>>(row_ptr, eidx, h_cur, Bagg);
        // h_nxt = relu([h|Bagg] @ Wcat^T + C)   — single-pass A, pipelined v4
        mgemm_wide<<<dim3(gN64, 1), 256, 0, stream>>>(h_cur, Bagg, Wcat, h_nxt, C, N_NODES);
        short* tmp = h_cur; h_cur = h_nxt; h_nxt = tmp;
    }

    // ---- node head (fused GEMM + log-softmax)
    head_kernel<<<gN64, 512, 0, stream>>>(h_cur, WzT, bz, out, N_NODES);

    // ---- edge head: node projections + per-edge combine
    nodeproj_kernel<<<2048, 256, 0, stream>>>(h_cur, Wg, eproj);
    edge_lsm_kernel<<<(E_EDGES + 255) / 256, 256, 0, stream>>>(ei, eproj, bg,
                                                               out + (size_t)N_NODES * VOCABSZ);
}

// Round 18
// 895.405 us; speedup vs baseline: 1.1346x; 1.1346x over previous
//
#include <hip/hip_runtime.h>
#include <hip/hip_bf16.h>
#include <cstdint>

#define N_NODES 50000
#define M_SRC   1024
#define E_EDGES 200000
#define EMB     256
#define HIDN    512
#define VOCABSZ 512
#define KW      1280   // wide GEMM K = 256 (h) + 1024 (Bagg)

typedef __attribute__((ext_vector_type(8))) short bf16x8;
typedef __attribute__((ext_vector_type(4))) short bf16x4;
typedef __attribute__((ext_vector_type(4))) float f32x4;

__device__ inline short f2b(float f) {
    __hip_bfloat16 b = __float2bfloat16(f);
    return *reinterpret_cast<short*>(&b);
}
__device__ inline float b2f(short s) {
    __hip_bfloat16 b = *reinterpret_cast<__hip_bfloat16*>(&s);
    return __bfloat162float(b);
}

// async global->LDS, 16B per lane. LDS dest = wave-uniform base + lane*16.
__device__ inline void gload16(const void* g, void* l) {
    __builtin_amdgcn_global_load_lds(
        (const __attribute__((address_space(1))) unsigned int*)g,
        (__attribute__((address_space(3))) unsigned int*)l,
        16, 0, 0);
}

// hardware transpose-read pair (earlyclobber: outputs must not alias addr reg)
__device__ inline void tr_read2(unsigned addr, bf16x4& lo, bf16x4& hi) {
    asm volatile("ds_read_b64_tr_b16 %0, %2\n\tds_read_b64_tr_b16 %1, %2 offset:512"
                 : "=&v"(lo), "=&v"(hi) : "v"(addr));
}

// ---------------------------------------------------------------- embedding -> bf16
__global__ void embed_kernel(const int* __restrict__ tgt_x,
                             const float* __restrict__ table,
                             short* __restrict__ h)
{
    int n = blockIdx.x, d = threadIdx.x;
    const int* tx = tgt_x + (size_t)n * 3;
    float s = table[(size_t)tx[0] * EMB + d]
            + table[(size_t)tx[1] * EMB + d]
            + table[(size_t)tx[2] * EMB + d];
    h[(size_t)n * EMB + d] = f2b(s);
}

// ---------------------------------------------------------------- fp32 -> bf16 flat convert
__global__ void convert_kernel(const float* __restrict__ in, short* __restrict__ out, int n)
{
    int i = blockIdx.x * 256 + threadIdx.x;
    if (i * 4 < n) {
        float4 v = *(const float4*)&in[i * 4];
        short4 o;
        o.x = f2b(v.x); o.y = f2b(v.y); o.z = f2b(v.z); o.w = f2b(v.w);
        *(short4*)&out[i * 4] = o;
    }
}

// ---------------------------------------------------------------- transpose to bf16
template<typename TIN>
__global__ void transpose_kernel(const TIN* __restrict__ in, short* __restrict__ out, int R, int C)
{
    __shared__ float t[32][33];
    int tx = threadIdx.x & 31, ty = threadIdx.x >> 5;   // 32 x 8
    int r0 = blockIdx.y * 32, c0 = blockIdx.x * 32;
#pragma unroll
    for (int i = 0; i < 4; i++) {
        int r = ty + i * 8;
        TIN v = in[(size_t)(r0 + r) * C + c0 + tx];
        if constexpr (sizeof(TIN) == 4) t[r][tx] = v;
        else                            t[r][tx] = b2f(v);
    }
    __syncthreads();
#pragma unroll
    for (int i = 0; i < 4; i++) {
        int r = ty + i * 8;
        out[(size_t)(c0 + r) * R + r0 + tx] = f2b(t[tx][r]);
    }
}

// ---------------------------------------------------------------- weight transposes -> Wcat [256][1280]
__global__ void transposeW_kernel(const float* __restrict__ Wh1, const float* __restrict__ Wh3,
                                  const float* __restrict__ Wr1, const float* __restrict__ Wr3,
                                  short* __restrict__ Wcat1, short* __restrict__ Wcat3)
{
    __shared__ float t[32][33];
    const int z = blockIdx.z;
    const float* in; short* outp; int coloff;
    if (z == 0)      { in = Wh1;                               outp = Wcat1; coloff = 0; }
    else if (z == 1) { in = Wh3;                               outp = Wcat3; coloff = 0; }
    else if (z < 6)  { in = Wr1 + (size_t)(z - 2) * EMB * EMB; outp = Wcat1; coloff = 256 + (z - 2) * 256; }
    else             { in = Wr3 + (size_t)(z - 6) * EMB * EMB; outp = Wcat3; coloff = 256 + (z - 6) * 256; }
    int tx = threadIdx.x & 31, ty = threadIdx.x >> 5;
    int r0 = blockIdx.y * 32, c0 = blockIdx.x * 32;
#pragma unroll
    for (int i = 0; i < 4; i++) {
        int r = ty + i * 8;
        t[r][tx] = in[(size_t)(r0 + r) * EMB + c0 + tx];
    }
    __syncthreads();
#pragma unroll
    for (int i = 0; i < 4; i++) {
        int r = ty + i * 8;
        outp[(size_t)(c0 + r) * KW + coloff + r0 + tx] = f2b(t[tx][r]);
    }
}

// ---------------------------------------------------------------- MFMA GEMM (r8-proven, MODE 0 only)
template<int MODE>
__global__ __launch_bounds__(256) void mgemm(
    const short* __restrict__ A, const short* __restrict__ BT,
    void* __restrict__ outp, const float* __restrict__ aux,
    const float* __restrict__ bias, int NR, int K, int J)
{
    __shared__ short As[128 * 40];
    __shared__ short Bs[128 * 40];
    const int tid  = threadIdx.x;
    const int n0   = blockIdx.x * 128;
    const int j0   = blockIdx.y * 128;
    const int lane = tid & 63, wid = tid >> 6;
    const int wr   = wid >> 1, wc = wid & 1;

    f32x4 acc[4][4];
#pragma unroll
    for (int m = 0; m < 4; m++)
#pragma unroll
        for (int n = 0; n < 4; n++) acc[m][n] = (f32x4){0.f, 0.f, 0.f, 0.f};

    for (int kt = 0; kt < K; kt += 32) {
#pragma unroll
        for (int r = 0; r < 2; r++) {
            int idx = tid + r * 256;
            int row = idx >> 2, ko = (idx & 3) * 8;
            int n = n0 + row;
            bf16x8 av = {0, 0, 0, 0, 0, 0, 0, 0};
            if (n < NR) av = *(const bf16x8*)&A[(size_t)n * K + kt + ko];
            *(bf16x8*)&As[row * 40 + ko] = av;
            *(bf16x8*)&Bs[row * 40 + ko] = *(const bf16x8*)&BT[(size_t)(j0 + row) * K + kt + ko];
        }
        __syncthreads();
        bf16x8 af[4], bfr[4];
#pragma unroll
        for (int m = 0; m < 4; m++)
            af[m] = *(const bf16x8*)&As[(wr * 64 + m * 16 + (lane & 15)) * 40 + (lane >> 4) * 8];
#pragma unroll
        for (int n = 0; n < 4; n++)
            bfr[n] = *(const bf16x8*)&Bs[(wc * 64 + n * 16 + (lane & 15)) * 40 + (lane >> 4) * 8];
#pragma unroll
        for (int m = 0; m < 4; m++)
#pragma unroll
            for (int n = 0; n < 4; n++)
                acc[m][n] = __builtin_amdgcn_mfma_f32_16x16x32_bf16(af[m], bfr[n], acc[m][n], 0, 0, 0);
        __syncthreads();
    }

#pragma unroll
    for (int m = 0; m < 4; m++) {
        int rbase = wr * 64 + m * 16 + ((lane >> 4) * 4);
#pragma unroll
        for (int r = 0; r < 4; r++) {
            int n_g = n0 + rbase + r;
            if (n_g >= NR) continue;
#pragma unroll
            for (int nn = 0; nn < 4; nn++) {
                int j_g = j0 + wc * 64 + nn * 16 + (lane & 15);
                ((short*)outp)[(size_t)n_g * J + j_g] = f2b(acc[m][nn][r]);
            }
        }
    }
}

// ---------------------------------------------------------------- wide GEMM v4 (aux in bf16)
// h_nxt = relu([h|Bagg] @ Wcat^T + C).  BM=64 x BN=256, BK=64, grid 782.
__global__ __launch_bounds__(256) void mgemm_wide(
    const short* __restrict__ A1, const short* __restrict__ A2,
    const short* __restrict__ BT, short* __restrict__ outp,
    const short* __restrict__ aux, int NR)
{
    __shared__ short As[2][4096];    // 2 subtiles (32x64) x dbuf = 16 KB
    __shared__ short Bs[2][16384];   // 8 subtiles x dbuf = 64 KB
    const int tid  = threadIdx.x;
    const int n0   = blockIdx.x * 64;
    const int lane = tid & 63, wid = tid >> 6;
    const int wr   = wid >> 1, wc = wid & 1;
    const int l4 = lane >> 4, l15 = lane & 15;

    auto SOFF = [](int r, int d8) {
        return (d8 & 1) * 8 + (r & 3) * 16 + ((r >> 3) & 3) * 64
             + ((r >> 2) & 1) * 256 + (d8 >> 1) * 512;
    };
    int a_row[2], a_d8[2];
#pragma unroll
    for (int q = 0; q < 2; q++) {
        int cig = tid + q * 256;
        int s = cig >> 8, ci = cig & 255;
        a_d8[q]  = (ci & 1) | (((ci >> 6) & 3) << 1);
        a_row[q] = s * 32 + (((ci >> 1) & 3) | (((ci >> 5) & 1) << 2) | (((ci >> 3) & 3) << 3));
    }
    int b_row[8], b_d8[8];
#pragma unroll
    for (int q = 0; q < 8; q++) {
        int cig = tid + q * 256;
        int s = cig >> 8, ci = cig & 255;
        b_d8[q]  = (ci & 1) | (((ci >> 6) & 3) << 1);
        b_row[q] = s * 32 + (((ci >> 1) & 3) | (((ci >> 5) & 1) << 2) | (((ci >> 3) & 3) << 3));
    }

    f32x4 acc[2][8];
#pragma unroll
    for (int m = 0; m < 2; m++)
#pragma unroll
        for (int n = 0; n < 8; n++) acc[m][n] = (f32x4){0.f, 0.f, 0.f, 0.f};

    auto STAGE = [&](int buf, int kt) {
#pragma unroll
        for (int q = 0; q < 2; q++) {
            int col = kt + a_d8[q] * 8;
            const short* src = (col < 256) ? &A1[(size_t)(n0 + a_row[q]) * 256 + col]
                                           : &A2[(size_t)(n0 + a_row[q]) * 1024 + (col - 256)];
            gload16(src, (char*)&As[buf][0] + q * 4096 + wid * 1024);
        }
#pragma unroll
        for (int q = 0; q < 8; q++) {
            gload16(&BT[(size_t)b_row[q] * KW + kt + b_d8[q] * 8],
                    (char*)&Bs[buf][0] + q * 4096 + wid * 1024);
        }
    };

    STAGE(0, 0);
    __syncthreads();

    for (int t = 0; t < 20; t++) {
        const int cur = t & 1;
        if (t + 1 < 20) STAGE(cur ^ 1, (t + 1) * 64);
#pragma unroll
        for (int kst = 0; kst < 2; kst++) {
            const int d8 = kst * 4 + l4;
            bf16x8 af[2], bfr[8];
#pragma unroll
            for (int m = 0; m < 2; m++)
                af[m] = *(const bf16x8*)&As[cur][wr * 2048 + SOFF(m * 16 + l15, d8)];
#pragma unroll
            for (int n = 0; n < 8; n++) {
                int sb = wc * 4 + (n >> 1);
                int r  = (n & 1) * 16 + l15;
                bfr[n] = *(const bf16x8*)&Bs[cur][sb * 2048 + SOFF(r, d8)];
            }
            __builtin_amdgcn_s_setprio(1);
#pragma unroll
            for (int m = 0; m < 2; m++)
#pragma unroll
                for (int n = 0; n < 8; n++)
                    acc[m][n] = __builtin_amdgcn_mfma_f32_16x16x32_bf16(af[m], bfr[n], acc[m][n], 0, 0, 0);
            __builtin_amdgcn_s_setprio(0);
        }
        __syncthreads();   // drains gload_lds for buf cur^1 + orders buffer reuse
    }

#pragma unroll
    for (int m = 0; m < 2; m++) {
        int rbase = wr * 32 + m * 16 + l4 * 4;
#pragma unroll
        for (int r = 0; r < 4; r++) {
            int n_g = n0 + rbase + r;
            if (n_g >= NR) continue;
#pragma unroll
            for (int nn = 0; nn < 8; nn++) {
                int j_g = wc * 128 + nn * 16 + l15;
                float v = acc[m][nn][r] + b2f(aux[(size_t)n_g * 256 + j_g]);
                outp[(size_t)n_g * 256 + j_g] = f2b(fmaxf(v, 0.f));
            }
        }
    }
}

// ---------------------------------------------------------------- fused flash attention v7b
// r16 structure (2-buffer, __syncthreads/chunk, bf16 C out) with PV tr-read
// groups software-pipelined: group-1 reads issue before group-0 MFMAs, so only
// ONE exposed lgkmcnt drain per chunk.
__global__ __launch_bounds__(128, 2) void attn_flash(
    const short* __restrict__ h, const short* __restrict__ kb,
    short* __restrict__ C, int NR)
{
    __shared__ short ks[2][32 * 256];   // 2 x 16 KB, subtiled layout
    __shared__ short Ps[64 * 36];       // wave-private rows, pad-36

    const int tid = threadIdx.x;
    const int lane = tid & 63, wv = tid >> 6;   // wv 0..1
    const int l4 = lane >> 4, l15 = lane & 15;
    const int n0 = blockIdx.x * 64;

    auto LOFF = [](int key, int d8) {
        return (d8 & 1) * 8 + (key & 3) * 16 + ((key >> 3) & 3) * 64
             + ((key >> 2) & 1) * 256 + (d8 >> 1) * 512;
    };
    int keyq[8], d8q[8];
#pragma unroll
    for (int q = 0; q < 8; q++) {
        int ci = wv * 64 + lane + q * 128;
        d8q[q]  = (ci & 1) | ((ci >> 6) << 1);
        keyq[q] = ((ci >> 1) & 3) | (((ci >> 5) & 1) << 2) | (((ci >> 3) & 3) << 3);
    }

    bf16x8 hreg[2][8];
#pragma unroll
    for (int rg = 0; rg < 2; rg++) {
        int n = n0 + wv * 32 + rg * 16 + l15;
        const short* hp = &h[(size_t)(n < NR ? n : 0) * 256 + l4 * 8];
#pragma unroll
        for (int kst = 0; kst < 8; kst++) hreg[rg][kst] = *(const bf16x8*)&hp[kst * 32];
        if (n >= NR) {
#pragma unroll
            for (int kst = 0; kst < 8; kst++) hreg[rg][kst] = (bf16x8){0, 0, 0, 0, 0, 0, 0, 0};
        }
    }

#pragma unroll
    for (int q = 0; q < 8; q++)
        gload16(&kb[(size_t)keyq[q] * 256 + d8q[q] * 8],
                (char*)&ks[0][0] + q * 2048 + wv * 1024);
    __syncthreads();

    const unsigned ksbase = (unsigned)(uintptr_t)&ks[0][0];
    const unsigned trlane = 2u * (unsigned)(l15 + l4 * 64);

    f32x4 oacc[2][16];
#pragma unroll
    for (int rg = 0; rg < 2; rg++)
#pragma unroll
        for (int mm = 0; mm < 16; mm++) oacc[rg][mm] = (f32x4){0.f, 0.f, 0.f, 0.f};
    float lsum[2] = {0.f, 0.f};

    for (int c = 0; c < 32; c++) {
        const int cur = c & 1;
        if (c + 1 < 32) {
            const short* kbn = kb + (size_t)(c + 1) * 32 * 256;
#pragma unroll
            for (int q = 0; q < 8; q++)
                gload16(&kbn[(size_t)keyq[q] * 256 + d8q[q] * 8],
                        (char*)&ks[cur ^ 1][0] + q * 2048 + wv * 1024);
        }

        f32x4 sacc[2][2];
#pragma unroll
        for (int rg = 0; rg < 2; rg++) {
            sacc[rg][0] = (f32x4){0.f, 0.f, 0.f, 0.f};
            sacc[rg][1] = (f32x4){0.f, 0.f, 0.f, 0.f};
        }
        __builtin_amdgcn_s_setprio(1);
#pragma unroll
        for (int kst = 0; kst < 8; kst++) {
#pragma unroll
            for (int m = 0; m < 2; m++) {
                int krow = m * 16 + l15;
                bf16x8 afk = *(const bf16x8*)&ks[cur][LOFF(krow, kst * 4 + l4)];
                sacc[0][m] = __builtin_amdgcn_mfma_f32_16x16x32_bf16(afk, hreg[0][kst], sacc[0][m], 0, 0, 0);
                sacc[1][m] = __builtin_amdgcn_mfma_f32_16x16x32_bf16(afk, hreg[1][kst], sacc[1][m], 0, 0, 0);
            }
        }
        __builtin_amdgcn_s_setprio(0);

#pragma unroll
        for (int rg = 0; rg < 2; rg++) {
            int prow = wv * 32 + rg * 16 + l15;
            float psum = 0.f;
#pragma unroll
            for (int m = 0; m < 2; m++) {
                float p0 = __expf(sacc[rg][m][0] * 0.0625f);
                float p1 = __expf(sacc[rg][m][1] * 0.0625f);
                float p2 = __expf(sacc[rg][m][2] * 0.0625f);
                float p3 = __expf(sacc[rg][m][3] * 0.0625f);
                psum += (p0 + p1) + (p2 + p3);
                short4 pk;
                pk.x = f2b(p0); pk.y = f2b(p1); pk.z = f2b(p2); pk.w = f2b(p3);
                *(short4*)&Ps[prow * 36 + m * 16 + l4 * 4] = pk;
            }
            psum += __shfl_xor(psum, 16);
            psum += __shfl_xor(psum, 32);
            lsum[rg] += psum;
        }

        // PV: pipelined tr-read groups — only one exposed drain per chunk
        bf16x8 bf2[2];
#pragma unroll
        for (int rg = 0; rg < 2; rg++)
            bf2[rg] = *(const bf16x8*)&Ps[(wv * 32 + rg * 16 + l15) * 36 + l4 * 8];
        unsigned trb = ksbase + (unsigned)(cur * 16384) + trlane;

        bf16x4 lo0[8], hi0[8], lo1[8], hi1[8];
#pragma unroll
        for (int q = 0; q < 8; q++)
            tr_read2(trb + (unsigned)(q * 1024), lo0[q], hi0[q]);
        asm volatile("s_waitcnt lgkmcnt(0)" ::: "memory");
        __builtin_amdgcn_sched_barrier(0);
        // issue group-1 reads now; their latency hides under group-0 MFMAs
#pragma unroll
        for (int q = 0; q < 8; q++)
            tr_read2(trb + (unsigned)((8 + q) * 1024), lo1[q], hi1[q]);
        __builtin_amdgcn_s_setprio(1);
#pragma unroll
        for (int q = 0; q < 8; q++) {
            bf16x8 af2;
#pragma unroll
            for (int t2 = 0; t2 < 4; t2++) { af2[t2] = lo0[q][t2]; af2[t2 + 4] = hi0[q][t2]; }
            oacc[0][q] = __builtin_amdgcn_mfma_f32_16x16x32_bf16(af2, bf2[0], oacc[0][q], 0, 0, 0);
            oacc[1][q] = __builtin_amdgcn_mfma_f32_16x16x32_bf16(af2, bf2[1], oacc[1][q], 0, 0, 0);
        }
        __builtin_amdgcn_s_setprio(0);
        asm volatile("s_waitcnt lgkmcnt(0)" ::: "memory");
        __builtin_amdgcn_sched_barrier(0);
        __builtin_amdgcn_s_setprio(1);
#pragma unroll
        for (int q = 0; q < 8; q++) {
            bf16x8 af2;
#pragma unroll
            for (int t2 = 0; t2 < 4; t2++) { af2[t2] = lo1[q][t2]; af2[t2 + 4] = hi1[q][t2]; }
            oacc[0][8 + q] = __builtin_amdgcn_mfma_f32_16x16x32_bf16(af2, bf2[0], oacc[0][8 + q], 0, 0, 0);
            oacc[1][8 + q] = __builtin_amdgcn_mfma_f32_16x16x32_bf16(af2, bf2[1], oacc[1][8 + q], 0, 0, 0);
        }
        __builtin_amdgcn_s_setprio(0);

        __syncthreads();
    }

#pragma unroll
    for (int rg = 0; rg < 2; rg++) {
        float li = 1.0f / lsum[rg];
        int hr = n0 + wv * 32 + rg * 16 + l15;
        if (hr >= NR) continue;
#pragma unroll
        for (int mm = 0; mm < 16; mm++) {
            short4 o;
            o.x = f2b(oacc[rg][mm][0] * li);
            o.y = f2b(oacc[rg][mm][1] * li);
            o.z = f2b(oacc[rg][mm][2] * li);
            o.w = f2b(oacc[rg][mm][3] * li);
            *(short4*)&C[(size_t)hr * 256 + mm * 16 + l4 * 4] = o;
        }
    }
}

// ---------------------------------------------------------------- CSR build (once per call)
__global__ void hist_kernel(const int* __restrict__ ei, int* __restrict__ deg)
{
    int e = blockIdx.x * 256 + threadIdx.x;
    if (e < E_EDGES) atomicAdd(&deg[ei[E_EDGES + e]], 1);
}

__global__ void scan1_kernel(const int* __restrict__ deg, int* __restrict__ incl,
                             int* __restrict__ bsum)
{
    __shared__ int s[256];
    int i = blockIdx.x * 256 + threadIdx.x;
    int v = (i < N_NODES) ? deg[i] : 0;
    s[threadIdx.x] = v;
    __syncthreads();
#pragma unroll
    for (int off = 1; off < 256; off <<= 1) {
        int t = (threadIdx.x >= off) ? s[threadIdx.x - off] : 0;
        __syncthreads();
        s[threadIdx.x] += t;
        __syncthreads();
    }
    if (i < N_NODES) incl[i] = s[threadIdx.x];
    if (threadIdx.x == 255) bsum[blockIdx.x] = s[255];
}

__global__ void scan2_kernel(int* __restrict__ bsum, int nb)
{
    __shared__ int s[256];
    int v = (threadIdx.x < nb) ? bsum[threadIdx.x] : 0;
    s[threadIdx.x] = v;
    __syncthreads();
#pragma unroll
    for (int off = 1; off < 256; off <<= 1) {
        int t = (threadIdx.x >= off) ? s[threadIdx.x - off] : 0;
        __syncthreads();
        s[threadIdx.x] += t;
        __syncthreads();
    }
    if (threadIdx.x < nb) bsum[threadIdx.x] = s[threadIdx.x];
}

__global__ void scan3_kernel(const int* __restrict__ deg, const int* __restrict__ incl,
                             const int* __restrict__ bsum, int* __restrict__ row_ptr,
                             int* __restrict__ cursor)
{
    int i = blockIdx.x * 256 + threadIdx.x;
    if (i >= N_NODES) return;
    int pref = (blockIdx.x > 0) ? bsum[blockIdx.x - 1] : 0;
    int start = pref + incl[i] - deg[i];
    row_ptr[i] = start;
    cursor[i]  = start;
    if (i == N_NODES - 1) row_ptr[N_NODES] = pref + incl[i];
}

__global__ void fill_kernel(const int* __restrict__ ei, const int* __restrict__ et,
                            int* __restrict__ cursor, int* __restrict__ eidx)
{
    int e = blockIdx.x * 256 + threadIdx.x;
    if (e >= E_EDGES) return;
    int tg = ei[E_EDGES + e];
    int slot = atomicAdd(&cursor[tg], 1);
    eidx[slot] = ei[e] | (et[e] << 16);   // src < 65536, type < 4
}

// ---------------------------------------------------------------- CSR gather of h into per-type buckets
__global__ void agg2_kernel(const int* __restrict__ row_ptr, const int* __restrict__ eidx,
                            const short* __restrict__ h, short* __restrict__ Bagg)
{
    int w = (blockIdx.x * 256 + threadIdx.x) >> 6;
    if (w >= N_NODES) return;
    int lane = threadIdx.x & 63;
    int s0 = row_ptr[w], s1 = row_ptr[w + 1];
    float a0[4] = {0, 0, 0, 0}, a1[4] = {0, 0, 0, 0}, a2[4] = {0, 0, 0, 0}, a3[4] = {0, 0, 0, 0};
    for (int i = s0; i < s1; i++) {
        int p = eidx[i];
        int s = p & 0xFFFF, t = p >> 16;   // t uniform across the wave
        short4 g = *(const short4*)&h[(size_t)s * EMB + lane * 4];
        float f0 = b2f(g.x), f1 = b2f(g.y), f2 = b2f(g.z), f3 = b2f(g.w);
        if (t == 0)      { a0[0] += f0; a0[1] += f1; a0[2] += f2; a0[3] += f3; }
        else if (t == 1) { a1[0] += f0; a1[1] += f1; a1[2] += f2; a1[3] += f3; }
        else if (t == 2) { a2[0] += f0; a2[1] += f1; a2[2] += f2; a2[3] += f3; }
        else             { a3[0] += f0; a3[1] += f1; a3[2] += f2; a3[3] += f3; }
    }
    short4 o;
    o.x = f2b(a0[0]); o.y = f2b(a0[1]); o.z = f2b(a0[2]); o.w = f2b(a0[3]);
    *(short4*)&Bagg[(size_t)w * 1024 + 0 * 256 + lane * 4] = o;
    o.x = f2b(a1[0]); o.y = f2b(a1[1]); o.z = f2b(a1[2]); o.w = f2b(a1[3]);
    *(short4*)&Bagg[(size_t)w * 1024 + 1 * 256 + lane * 4] = o;
    o.x = f2b(a2[0]); o.y = f2b(a2[1]); o.z = f2b(a2[2]); o.w = f2b(a2[3]);
    *(short4*)&Bagg[(size_t)w * 1024 + 2 * 256 + lane * 4] = o;
    o.x = f2b(a3[0]); o.y = f2b(a3[1]); o.z = f2b(a3[2]); o.w = f2b(a3[3]);
    *(short4*)&Bagg[(size_t)w * 1024 + 3 * 256 + lane * 4] = o;
}

// ---------------------------------------------------------------- fused node head
__global__ __launch_bounds__(512, 2) void head_kernel(
    const short* __restrict__ hmat, const short* __restrict__ WzT,
    const float* __restrict__ bz, float* __restrict__ out, int NR)
{
    __shared__ short hs[64 * 256];   // swizzled
    __shared__ float redm[64 * 8];
    __shared__ float reds[64 * 8];

    const int tid = threadIdx.x;
    const int lane = tid & 63, wv = tid >> 6;  // wv 0..7
    const int l4 = lane >> 4, l15 = lane & 15;
    const int n0 = blockIdx.x * 64;

#pragma unroll
    for (int i = 0; i < 4; i++) {
        int idx = tid + i * 512;
        int row = idx >> 5, kg = idx & 31;
        bf16x8 v = {0, 0, 0, 0, 0, 0, 0, 0};
        if (n0 + row < NR) v = *(const bf16x8*)&hmat[(size_t)(n0 + row) * 256 + kg * 8];
        *(bf16x8*)&hs[(row * 256 + kg * 8) ^ ((row & 7) << 3)] = v;
    }
    __syncthreads();

    f32x4 acc[4][4];
#pragma unroll
    for (int m = 0; m < 4; m++)
#pragma unroll
        for (int n = 0; n < 4; n++) acc[m][n] = (f32x4){0.f, 0.f, 0.f, 0.f};

#pragma unroll
    for (int kt = 0; kt < 256; kt += 32) {
        bf16x8 af[4], bfr[4];
#pragma unroll
        for (int m = 0; m < 4; m++) {
            int row = m * 16 + l15;
            af[m] = *(const bf16x8*)&hs[(row * 256 + kt + l4 * 8) ^ ((row & 7) << 3)];
        }
#pragma unroll
        for (int n = 0; n < 4; n++) {
            int col = wv * 64 + n * 16 + l15;
            bfr[n] = *(const bf16x8*)&WzT[(size_t)col * 256 + kt + l4 * 8];
        }
#pragma unroll
        for (int m = 0; m < 4; m++)
#pragma unroll
            for (int n = 0; n < 4; n++)
                acc[m][n] = __builtin_amdgcn_mfma_f32_16x16x32_bf16(af[m], bfr[n], acc[m][n], 0, 0, 0);
    }

    float bcol[4];
#pragma unroll
    for (int n = 0; n < 4; n++) bcol[n] = bz[wv * 64 + n * 16 + l15];
#pragma unroll
    for (int m = 0; m < 4; m++)
#pragma unroll
        for (int n = 0; n < 4; n++)
#pragma unroll
            for (int r = 0; r < 4; r++) acc[m][n][r] += bcol[n];

    float lg[4][4];
#pragma unroll
    for (int m = 0; m < 4; m++)
#pragma unroll
        for (int r = 0; r < 4; r++) {
            float v = fmaxf(fmaxf(acc[m][0][r], acc[m][1][r]), fmaxf(acc[m][2][r], acc[m][3][r]));
            v = fmaxf(v, __shfl_xor(v, 1));
            v = fmaxf(v, __shfl_xor(v, 2));
            v = fmaxf(v, __shfl_xor(v, 4));
            v = fmaxf(v, __shfl_xor(v, 8));
            if (l15 == 0) redm[(m * 16 + l4 * 4 + r) * 8 + wv] = v;
        }
    __syncthreads();
#pragma unroll
    for (int m = 0; m < 4; m++)
#pragma unroll
        for (int r = 0; r < 4; r++) {
            int row = m * 16 + l4 * 4 + r;
            float v = redm[row * 8 + 0];
#pragma unroll
            for (int w = 1; w < 8; w++) v = fmaxf(v, redm[row * 8 + w]);
            lg[m][r] = v;
        }
#pragma unroll
    for (int m = 0; m < 4; m++)
#pragma unroll
        for (int r = 0; r < 4; r++) {
            float gm = lg[m][r];
            float s = __expf(acc[m][0][r] - gm) + __expf(acc[m][1][r] - gm)
                    + __expf(acc[m][2][r] - gm) + __expf(acc[m][3][r] - gm);
            s += __shfl_xor(s, 1);
            s += __shfl_xor(s, 2);
            s += __shfl_xor(s, 4);
            s += __shfl_xor(s, 8);
            if (l15 == 0) reds[(m * 16 + l4 * 4 + r) * 8 + wv] = s;
        }
    __syncthreads();
#pragma unroll
    for (int m = 0; m < 4; m++)
#pragma unroll
        for (int r = 0; r < 4; r++) {
            int row = m * 16 + l4 * 4 + r;
            float s = reds[row * 8 + 0];
#pragma unroll
            for (int w = 1; w < 8; w++) s += reds[row * 8 + w];
            lg[m][r] += __logf(s);
        }
#pragma unroll
    for (int m = 0; m < 4; m++)
#pragma unroll
        for (int r = 0; r < 4; r++) {
            int hr = n0 + m * 16 + l4 * 4 + r;
            if (hr >= NR) continue;
#pragma unroll
            for (int n = 0; n < 4; n++)
                out[(size_t)hr * VOCABSZ + wv * 64 + n * 16 + l15] = acc[m][n][r] - lg[m][r];
        }
}

// ---------------------------------------------------------------- node projections for edge head
__global__ __launch_bounds__(256) void nodeproj_kernel(
    const short* __restrict__ h, const float* __restrict__ Wg,
    float* __restrict__ eproj)
{
    int lane = threadIdx.x & 63;
    int gw   = (blockIdx.x * 256 + threadIdx.x) >> 6;
    int nw   = (gridDim.x * 256) >> 6;
    float ws[4][5], wt[4][5];
#pragma unroll
    for (int c = 0; c < 4; c++)
#pragma unroll
        for (int j = 0; j < 5; j++) {
            ws[c][j] = Wg[(size_t)(lane * 4 + c) * 5 + j];
            wt[c][j] = Wg[(size_t)(256 + lane * 4 + c) * 5 + j];
        }

    for (int n = gw; n < N_NODES; n += nw) {
        short4 hv = *(const short4*)&h[(size_t)n * EMB + lane * 4];
        float f[4] = { b2f(hv.x), b2f(hv.y), b2f(hv.z), b2f(hv.w) };
        float a[5] = {0, 0, 0, 0, 0}, b[5] = {0, 0, 0, 0, 0};
#pragma unroll
        for (int c = 0; c < 4; c++)
#pragma unroll
            for (int j = 0; j < 5; j++) {
                a[j] += f[c] * ws[c][j];
                b[j] += f[c] * wt[c][j];
            }
#pragma unroll
        for (int j = 0; j < 5; j++)
#pragma unroll
            for (int off = 32; off; off >>= 1) {
                a[j] += __shfl_xor(a[j], off);
                b[j] += __shfl_xor(b[j], off);
            }
        if (lane == 0) {
#pragma unroll
            for (int j = 0; j < 5; j++) {
                eproj[(size_t)n * 10 + j]     = a[j];
                eproj[(size_t)n * 10 + 5 + j] = b[j];
            }
        }
    }
}

// ---------------------------------------------------------------- edge head combine
__global__ void edge_lsm_kernel(const int* __restrict__ ei,
                                const float* __restrict__ eproj,
                                const float* __restrict__ bg,
                                float* __restrict__ out)
{
    int e = blockIdx.x * 256 + threadIdx.x;
    if (e >= E_EDGES) return;
    int s = ei[e], t = ei[E_EDGES + e];
    const float* ps = &eproj[(size_t)s * 10];
    const float* pt = &eproj[(size_t)t * 10 + 5];
    float z[5];
#pragma unroll
    for (int j = 0; j < 5; j++) z[j] = ps[j] + pt[j] + bg[j];
    float mm = fmaxf(fmaxf(fmaxf(z[0], z[1]), fmaxf(z[2], z[3])), z[4]);
    float ss = __expf(z[0] - mm) + __expf(z[1] - mm) + __expf(z[2] - mm)
             + __expf(z[3] - mm) + __expf(z[4] - mm);
    float lg = mm + __logf(ss);
    float* o = &out[(size_t)e * 5];
#pragma unroll
    for (int j = 0; j < 5; j++) o[j] = z[j] - lg;
}

// ---------------------------------------------------------------- launch
extern "C" void kernel_launch(void* const* d_in, const int* in_sizes, int n_in,
                              void* d_out, int out_size, void* d_ws, size_t ws_size,
                              hipStream_t stream)
{
    const int*   tgt_x = (const int*)  d_in[0];
    const float* x     = (const float*)d_in[1];
    const int*   ei    = (const int*)  d_in[2];
    const int*   et    = (const int*)  d_in[3];
    const float* table = (const float*)d_in[4];
    const float* Wh1   = (const float*)d_in[5];
    const float* Wrel1 = (const float*)d_in[6];
    const float* Wsrc1 = (const float*)d_in[7];
    const float* Wh3   = (const float*)d_in[8];
    const float* Wrel3 = (const float*)d_in[9];
    const float* Wsrc3 = (const float*)d_in[10];
    const float* Wz    = (const float*)d_in[11];
    const float* bz    = (const float*)d_in[12];
    const float* Wg    = (const float*)d_in[13];
    const float* bg    = (const float*)d_in[14];
    float* out = (float*)d_out;

    // ---- workspace layout
    short* h_a = (short*)d_ws;                              // N*256 bf16
    short* h_b = h_a + (size_t)N_NODES * EMB;
    short* C   = h_b + (size_t)N_NODES * EMB;               // N*256 bf16 (ctx)
    short* Bagg = C + (size_t)N_NODES * EMB;                // N*1024 bf16
    short* k1b = Bagg + (size_t)N_NODES * 1024;             // [1024][256]
    short* k3b = k1b + M_SRC * EMB;
    short* x_b = k3b + M_SRC * EMB;                         // [1024][512]
    short* WsT1 = x_b + M_SRC * HIDN;                       // [256][512]
    short* WsT3 = WsT1 + EMB * HIDN;
    short* Wcat1 = WsT3 + EMB * HIDN;                       // [256][1280]
    short* Wcat3 = Wcat1 + EMB * KW;
    short* WzT  = Wcat3 + EMB * KW;                         // [512][256]
    int* deg     = (int*)(WzT + VOCABSZ * EMB);             // N
    int* incl    = deg + N_NODES;                           // N
    int* bsum    = incl + N_NODES;                          // 256
    int* row_ptr = bsum + 256;                              // N+1
    int* cursor  = row_ptr + N_NODES + 1;                   // N
    int* eidx    = cursor + N_NODES;                        // E
    float* eproj = (float*)(eidx + E_EDGES);                // N*10 f32

    const int gN64 = (N_NODES + 63) / 64;                   // 782
    const int nb1 = (N_NODES + 255) / 256;                  // 196

    // ---- CSR build (edges constant across layers)
    hipMemsetAsync(deg, 0, N_NODES * sizeof(int), stream);
    hist_kernel<<<(E_EDGES + 255) / 256, 256, 0, stream>>>(ei, deg);
    scan1_kernel<<<nb1, 256, 0, stream>>>(deg, incl, bsum);
    scan2_kernel<<<1, 256, 0, stream>>>(bsum, nb1);
    scan3_kernel<<<nb1, 256, 0, stream>>>(deg, incl, bsum, row_ptr, cursor);
    fill_kernel<<<(E_EDGES + 255) / 256, 256, 0, stream>>>(ei, et, cursor, eidx);

    // ---- weight prep
    convert_kernel<<<(M_SRC * HIDN / 4 + 255) / 256, 256, 0, stream>>>(x, x_b, M_SRC * HIDN);
    transpose_kernel<float><<<dim3(EMB / 32, HIDN / 32), 256, 0, stream>>>(Wsrc1, WsT1, HIDN, EMB);
    transpose_kernel<float><<<dim3(EMB / 32, HIDN / 32), 256, 0, stream>>>(Wsrc3, WsT3, HIDN, EMB);
    transposeW_kernel<<<dim3(8, 8, 10), 256, 0, stream>>>(Wh1, Wh3, Wrel1, Wrel3, Wcat1, Wcat3);
    transpose_kernel<float><<<dim3(VOCABSZ / 32, EMB / 32), 256, 0, stream>>>(Wz, WzT, EMB, VOCABSZ);

    // ---- k = x @ Wsrc (bf16)
    mgemm<0><<<dim3(M_SRC / 128, EMB / 128), 256, 0, stream>>>(x_b, WsT1, k1b, nullptr, nullptr, M_SRC, HIDN, EMB);
    mgemm<0><<<dim3(M_SRC / 128, EMB / 128), 256, 0, stream>>>(x_b, WsT3, k3b, nullptr, nullptr, M_SRC, HIDN, EMB);

    // ---- embedding
    embed_kernel<<<N_NODES, 256, 0, stream>>>(tgt_x, table, h_a);

    short* h_cur = h_a;
    short* h_nxt = h_b;
    for (int layer = 0; layer < 3; layer++) {
        const short* kb   = (layer < 2) ? k1b   : k3b;
        const short* Wcat = (layer < 2) ? Wcat1 : Wcat3;

        // C = softmax(h k^T / 16) @ k   (fused flash v7b)
        attn_flash<<<gN64, 128, 0, stream>>>(h_cur, kb, C, N_NODES);
        // Bagg[tgt] = per-type sums of h[src]
        agg2_kernel<<<(N_NODES + 3) / 4, 256, 0, stream>>>(row_ptr, eidx, h_cur, Bagg);
        // h_nxt = relu([h|Bagg] @ Wcat^T + C)   — single-pass A, pipelined v4
        mgemm_wide<<<dim3(gN64, 1), 256, 0, stream>>>(h_cur, Bagg, Wcat, h_nxt, C, N_NODES);
        short* tmp = h_cur; h_cur = h_nxt; h_nxt = tmp;
    }

    // ---- node head (fused GEMM + log-softmax)
    head_kernel<<<gN64, 512, 0, stream>>>(h_cur, WzT, bz, out, N_NODES);

    // ---- edge head: node projections + per-edge combine
    nodeproj_kernel<<<2048, 256, 0, stream>>>(h_cur, Wg, eproj);
    edge_lsm_kernel<<<(E_EDGES + 255) / 256, 256, 0, stream>>>(ei, eproj, bg,
                                                               out + (size_t)N_NODES * VOCABSZ);
}

// Round 19
// 760.707 us; speedup vs baseline: 1.3355x; 1.1771x over previous
//
#include <hip/hip_runtime.h>
#include <hip/hip_bf16.h>
#include <cstdint>

#define N_NODES 50000
#define M_SRC   1024
#define E_EDGES 200000
#define EMB     256
#define HIDN    512
#define VOCABSZ 512
#define KW      1280   // wide GEMM K = 256 (h) + 1024 (Bagg)

typedef __attribute__((ext_vector_type(8))) short bf16x8;
typedef __attribute__((ext_vector_type(4))) short bf16x4;
typedef __attribute__((ext_vector_type(4))) float f32x4;

__device__ inline short f2b(float f) {
    __hip_bfloat16 b = __float2bfloat16(f);
    return *reinterpret_cast<short*>(&b);
}
__device__ inline float b2f(short s) {
    __hip_bfloat16 b = *reinterpret_cast<__hip_bfloat16*>(&s);
    return __bfloat162float(b);
}

// async global->LDS, 16B per lane. LDS dest = wave-uniform base + lane*16.
__device__ inline void gload16(const void* g, void* l) {
    __builtin_amdgcn_global_load_lds(
        (const __attribute__((address_space(1))) unsigned int*)g,
        (__attribute__((address_space(3))) unsigned int*)l,
        16, 0, 0);
}

// hardware transpose-read pair (earlyclobber: outputs must not alias addr reg)
__device__ inline void tr_read2(unsigned addr, bf16x4& lo, bf16x4& hi) {
    asm volatile("ds_read_b64_tr_b16 %0, %2\n\tds_read_b64_tr_b16 %1, %2 offset:512"
                 : "=&v"(lo), "=&v"(hi) : "v"(addr));
}

// ---------------------------------------------------------------- embedding -> bf16
__global__ void embed_kernel(const int* __restrict__ tgt_x,
                             const float* __restrict__ table,
                             short* __restrict__ h)
{
    int n = blockIdx.x, d = threadIdx.x;
    const int* tx = tgt_x + (size_t)n * 3;
    float s = table[(size_t)tx[0] * EMB + d]
            + table[(size_t)tx[1] * EMB + d]
            + table[(size_t)tx[2] * EMB + d];
    h[(size_t)n * EMB + d] = f2b(s);
}

// ---------------------------------------------------------------- fp32 -> bf16 flat convert
__global__ void convert_kernel(const float* __restrict__ in, short* __restrict__ out, int n)
{
    int i = blockIdx.x * 256 + threadIdx.x;
    if (i * 4 < n) {
        float4 v = *(const float4*)&in[i * 4];
        short4 o;
        o.x = f2b(v.x); o.y = f2b(v.y); o.z = f2b(v.z); o.w = f2b(v.w);
        *(short4*)&out[i * 4] = o;
    }
}

// ---------------------------------------------------------------- transpose to bf16
template<typename TIN>
__global__ void transpose_kernel(const TIN* __restrict__ in, short* __restrict__ out, int R, int C)
{
    __shared__ float t[32][33];
    int tx = threadIdx.x & 31, ty = threadIdx.x >> 5;   // 32 x 8
    int r0 = blockIdx.y * 32, c0 = blockIdx.x * 32;
#pragma unroll
    for (int i = 0; i < 4; i++) {
        int r = ty + i * 8;
        TIN v = in[(size_t)(r0 + r) * C + c0 + tx];
        if constexpr (sizeof(TIN) == 4) t[r][tx] = v;
        else                            t[r][tx] = b2f(v);
    }
    __syncthreads();
#pragma unroll
    for (int i = 0; i < 4; i++) {
        int r = ty + i * 8;
        out[(size_t)(c0 + r) * R + r0 + tx] = f2b(t[tx][r]);
    }
}

// ---------------------------------------------------------------- weight transposes -> Wcat [256][1280]
__global__ void transposeW_kernel(const float* __restrict__ Wh1, const float* __restrict__ Wh3,
                                  const float* __restrict__ Wr1, const float* __restrict__ Wr3,
                                  short* __restrict__ Wcat1, short* __restrict__ Wcat3)
{
    __shared__ float t[32][33];
    const int z = blockIdx.z;
    const float* in; short* outp; int coloff;
    if (z == 0)      { in = Wh1;                               outp = Wcat1; coloff = 0; }
    else if (z == 1) { in = Wh3;                               outp = Wcat3; coloff = 0; }
    else if (z < 6)  { in = Wr1 + (size_t)(z - 2) * EMB * EMB; outp = Wcat1; coloff = 256 + (z - 2) * 256; }
    else             { in = Wr3 + (size_t)(z - 6) * EMB * EMB; outp = Wcat3; coloff = 256 + (z - 6) * 256; }
    int tx = threadIdx.x & 31, ty = threadIdx.x >> 5;
    int r0 = blockIdx.y * 32, c0 = blockIdx.x * 32;
#pragma unroll
    for (int i = 0; i < 4; i++) {
        int r = ty + i * 8;
        t[r][tx] = in[(size_t)(r0 + r) * EMB + c0 + tx];
    }
    __syncthreads();
#pragma unroll
    for (int i = 0; i < 4; i++) {
        int r = ty + i * 8;
        outp[(size_t)(c0 + r) * KW + coloff + r0 + tx] = f2b(t[tx][r]);
    }
}

// ---------------------------------------------------------------- MFMA GEMM (r8-proven, MODE 0 only)
template<int MODE>
__global__ __launch_bounds__(256) void mgemm(
    const short* __restrict__ A, const short* __restrict__ BT,
    void* __restrict__ outp, const float* __restrict__ aux,
    const float* __restrict__ bias, int NR, int K, int J)
{
    __shared__ short As[128 * 40];
    __shared__ short Bs[128 * 40];
    const int tid  = threadIdx.x;
    const int n0   = blockIdx.x * 128;
    const int j0   = blockIdx.y * 128;
    const int lane = tid & 63, wid = tid >> 6;
    const int wr   = wid >> 1, wc = wid & 1;

    f32x4 acc[4][4];
#pragma unroll
    for (int m = 0; m < 4; m++)
#pragma unroll
        for (int n = 0; n < 4; n++) acc[m][n] = (f32x4){0.f, 0.f, 0.f, 0.f};

    for (int kt = 0; kt < K; kt += 32) {
#pragma unroll
        for (int r = 0; r < 2; r++) {
            int idx = tid + r * 256;
            int row = idx >> 2, ko = (idx & 3) * 8;
            int n = n0 + row;
            bf16x8 av = {0, 0, 0, 0, 0, 0, 0, 0};
            if (n < NR) av = *(const bf16x8*)&A[(size_t)n * K + kt + ko];
            *(bf16x8*)&As[row * 40 + ko] = av;
            *(bf16x8*)&Bs[row * 40 + ko] = *(const bf16x8*)&BT[(size_t)(j0 + row) * K + kt + ko];
        }
        __syncthreads();
        bf16x8 af[4], bfr[4];
#pragma unroll
        for (int m = 0; m < 4; m++)
            af[m] = *(const bf16x8*)&As[(wr * 64 + m * 16 + (lane & 15)) * 40 + (lane >> 4) * 8];
#pragma unroll
        for (int n = 0; n < 4; n++)
            bfr[n] = *(const bf16x8*)&Bs[(wc * 64 + n * 16 + (lane & 15)) * 40 + (lane >> 4) * 8];
#pragma unroll
        for (int m = 0; m < 4; m++)
#pragma unroll
            for (int n = 0; n < 4; n++)
                acc[m][n] = __builtin_amdgcn_mfma_f32_16x16x32_bf16(af[m], bfr[n], acc[m][n], 0, 0, 0);
        __syncthreads();
    }

#pragma unroll
    for (int m = 0; m < 4; m++) {
        int rbase = wr * 64 + m * 16 + ((lane >> 4) * 4);
#pragma unroll
        for (int r = 0; r < 4; r++) {
            int n_g = n0 + rbase + r;
            if (n_g >= NR) continue;
#pragma unroll
            for (int nn = 0; nn < 4; nn++) {
                int j_g = j0 + wc * 64 + nn * 16 + (lane & 15);
                ((short*)outp)[(size_t)n_g * J + j_g] = f2b(acc[m][nn][r]);
            }
        }
    }
}

// ---------------------------------------------------------------- wide GEMM v4 (aux in bf16)
// h_nxt = relu([h|Bagg] @ Wcat^T + C).  BM=64 x BN=256, BK=64, grid 782.
__global__ __launch_bounds__(256) void mgemm_wide(
    const short* __restrict__ A1, const short* __restrict__ A2,
    const short* __restrict__ BT, short* __restrict__ outp,
    const short* __restrict__ aux, int NR)
{
    __shared__ short As[2][4096];    // 2 subtiles (32x64) x dbuf = 16 KB
    __shared__ short Bs[2][16384];   // 8 subtiles x dbuf = 64 KB
    const int tid  = threadIdx.x;
    const int n0   = blockIdx.x * 64;
    const int lane = tid & 63, wid = tid >> 6;
    const int wr   = wid >> 1, wc = wid & 1;
    const int l4 = lane >> 4, l15 = lane & 15;

    auto SOFF = [](int r, int d8) {
        return (d8 & 1) * 8 + (r & 3) * 16 + ((r >> 3) & 3) * 64
             + ((r >> 2) & 1) * 256 + (d8 >> 1) * 512;
    };
    int a_row[2], a_d8[2];
#pragma unroll
    for (int q = 0; q < 2; q++) {
        int cig = tid + q * 256;
        int s = cig >> 8, ci = cig & 255;
        a_d8[q]  = (ci & 1) | (((ci >> 6) & 3) << 1);
        a_row[q] = s * 32 + (((ci >> 1) & 3) | (((ci >> 5) & 1) << 2) | (((ci >> 3) & 3) << 3));
    }
    int b_row[8], b_d8[8];
#pragma unroll
    for (int q = 0; q < 8; q++) {
        int cig = tid + q * 256;
        int s = cig >> 8, ci = cig & 255;
        b_d8[q]  = (ci & 1) | (((ci >> 6) & 3) << 1);
        b_row[q] = s * 32 + (((ci >> 1) & 3) | (((ci >> 5) & 1) << 2) | (((ci >> 3) & 3) << 3));
    }

    f32x4 acc[2][8];
#pragma unroll
    for (int m = 0; m < 2; m++)
#pragma unroll
        for (int n = 0; n < 8; n++) acc[m][n] = (f32x4){0.f, 0.f, 0.f, 0.f};

    auto STAGE = [&](int buf, int kt) {
#pragma unroll
        for (int q = 0; q < 2; q++) {
            int col = kt + a_d8[q] * 8;
            const short* src = (col < 256) ? &A1[(size_t)(n0 + a_row[q]) * 256 + col]
                                           : &A2[(size_t)(n0 + a_row[q]) * 1024 + (col - 256)];
            gload16(src, (char*)&As[buf][0] + q * 4096 + wid * 1024);
        }
#pragma unroll
        for (int q = 0; q < 8; q++) {
            gload16(&BT[(size_t)b_row[q] * KW + kt + b_d8[q] * 8],
                    (char*)&Bs[buf][0] + q * 4096 + wid * 1024);
        }
    };

    STAGE(0, 0);
    __syncthreads();

    for (int t = 0; t < 20; t++) {
        const int cur = t & 1;
        if (t + 1 < 20) STAGE(cur ^ 1, (t + 1) * 64);
#pragma unroll
        for (int kst = 0; kst < 2; kst++) {
            const int d8 = kst * 4 + l4;
            bf16x8 af[2], bfr[8];
#pragma unroll
            for (int m = 0; m < 2; m++)
                af[m] = *(const bf16x8*)&As[cur][wr * 2048 + SOFF(m * 16 + l15, d8)];
#pragma unroll
            for (int n = 0; n < 8; n++) {
                int sb = wc * 4 + (n >> 1);
                int r  = (n & 1) * 16 + l15;
                bfr[n] = *(const bf16x8*)&Bs[cur][sb * 2048 + SOFF(r, d8)];
            }
            __builtin_amdgcn_s_setprio(1);
#pragma unroll
            for (int m = 0; m < 2; m++)
#pragma unroll
                for (int n = 0; n < 8; n++)
                    acc[m][n] = __builtin_amdgcn_mfma_f32_16x16x32_bf16(af[m], bfr[n], acc[m][n], 0, 0, 0);
            __builtin_amdgcn_s_setprio(0);
        }
        __syncthreads();   // drains gload_lds for buf cur^1 + orders buffer reuse
    }

#pragma unroll
    for (int m = 0; m < 2; m++) {
        int rbase = wr * 32 + m * 16 + l4 * 4;
#pragma unroll
        for (int r = 0; r < 4; r++) {
            int n_g = n0 + rbase + r;
            if (n_g >= NR) continue;
#pragma unroll
            for (int nn = 0; nn < 8; nn++) {
                int j_g = wc * 128 + nn * 16 + l15;
                float v = acc[m][nn][r] + b2f(aux[(size_t)n_g * 256 + j_g]);
                outp[(size_t)n_g * 256 + j_g] = f2b(fmaxf(v, 0.f));
            }
        }
    }
}

// ---------------------------------------------------------------- fused flash attention v7 (bf16 C out)
__global__ __launch_bounds__(128, 2) void attn_flash(
    const short* __restrict__ h, const short* __restrict__ kb,
    short* __restrict__ C, int NR)
{
    __shared__ short ks[2][32 * 256];   // 2 x 16 KB, subtiled layout
    __shared__ short Ps[64 * 36];       // wave-private rows, pad-36

    const int tid = threadIdx.x;
    const int lane = tid & 63, wv = tid >> 6;   // wv 0..1
    const int l4 = lane >> 4, l15 = lane & 15;
    const int n0 = blockIdx.x * 64;

    auto LOFF = [](int key, int d8) {
        return (d8 & 1) * 8 + (key & 3) * 16 + ((key >> 3) & 3) * 64
             + ((key >> 2) & 1) * 256 + (d8 >> 1) * 512;
    };
    int keyq[8], d8q[8];
#pragma unroll
    for (int q = 0; q < 8; q++) {
        int ci = wv * 64 + lane + q * 128;
        d8q[q]  = (ci & 1) | ((ci >> 6) << 1);
        keyq[q] = ((ci >> 1) & 3) | (((ci >> 5) & 1) << 2) | (((ci >> 3) & 3) << 3);
    }

    bf16x8 hreg[2][8];
#pragma unroll
    for (int rg = 0; rg < 2; rg++) {
        int n = n0 + wv * 32 + rg * 16 + l15;
        const short* hp = &h[(size_t)(n < NR ? n : 0) * 256 + l4 * 8];
#pragma unroll
        for (int kst = 0; kst < 8; kst++) hreg[rg][kst] = *(const bf16x8*)&hp[kst * 32];
        if (n >= NR) {
#pragma unroll
            for (int kst = 0; kst < 8; kst++) hreg[rg][kst] = (bf16x8){0, 0, 0, 0, 0, 0, 0, 0};
        }
    }

#pragma unroll
    for (int q = 0; q < 8; q++)
        gload16(&kb[(size_t)keyq[q] * 256 + d8q[q] * 8],
                (char*)&ks[0][0] + q * 2048 + wv * 1024);
    __syncthreads();

    const unsigned ksbase = (unsigned)(uintptr_t)&ks[0][0];
    const unsigned trlane = 2u * (unsigned)(l15 + l4 * 64);

    f32x4 oacc[2][16];
#pragma unroll
    for (int rg = 0; rg < 2; rg++)
#pragma unroll
        for (int mm = 0; mm < 16; mm++) oacc[rg][mm] = (f32x4){0.f, 0.f, 0.f, 0.f};
    float lsum[2] = {0.f, 0.f};

    for (int c = 0; c < 32; c++) {
        const int cur = c & 1;
        if (c + 1 < 32) {
            const short* kbn = kb + (size_t)(c + 1) * 32 * 256;
#pragma unroll
            for (int q = 0; q < 8; q++)
                gload16(&kbn[(size_t)keyq[q] * 256 + d8q[q] * 8],
                        (char*)&ks[cur ^ 1][0] + q * 2048 + wv * 1024);
        }

        f32x4 sacc[2][2];
#pragma unroll
        for (int rg = 0; rg < 2; rg++) {
            sacc[rg][0] = (f32x4){0.f, 0.f, 0.f, 0.f};
            sacc[rg][1] = (f32x4){0.f, 0.f, 0.f, 0.f};
        }
        __builtin_amdgcn_s_setprio(1);
#pragma unroll
        for (int kst = 0; kst < 8; kst++) {
#pragma unroll
            for (int m = 0; m < 2; m++) {
                int krow = m * 16 + l15;
                bf16x8 afk = *(const bf16x8*)&ks[cur][LOFF(krow, kst * 4 + l4)];
                sacc[0][m] = __builtin_amdgcn_mfma_f32_16x16x32_bf16(afk, hreg[0][kst], sacc[0][m], 0, 0, 0);
                sacc[1][m] = __builtin_amdgcn_mfma_f32_16x16x32_bf16(afk, hreg[1][kst], sacc[1][m], 0, 0, 0);
            }
        }
        __builtin_amdgcn_s_setprio(0);

#pragma unroll
        for (int rg = 0; rg < 2; rg++) {
            int prow = wv * 32 + rg * 16 + l15;
            float psum = 0.f;
#pragma unroll
            for (int m = 0; m < 2; m++) {
                float p0 = __expf(sacc[rg][m][0] * 0.0625f);
                float p1 = __expf(sacc[rg][m][1] * 0.0625f);
                float p2 = __expf(sacc[rg][m][2] * 0.0625f);
                float p3 = __expf(sacc[rg][m][3] * 0.0625f);
                psum += (p0 + p1) + (p2 + p3);
                short4 pk;
                pk.x = f2b(p0); pk.y = f2b(p1); pk.z = f2b(p2); pk.w = f2b(p3);
                *(short4*)&Ps[prow * 36 + m * 16 + l4 * 4] = pk;
            }
            psum += __shfl_xor(psum, 16);
            psum += __shfl_xor(psum, 32);
            lsum[rg] += psum;
        }

        bf16x8 bf2[2];
#pragma unroll
        for (int rg = 0; rg < 2; rg++)
            bf2[rg] = *(const bf16x8*)&Ps[(wv * 32 + rg * 16 + l15) * 36 + l4 * 8];
        unsigned trb = ksbase + (unsigned)(cur * 16384) + trlane;
#pragma unroll
        for (int g = 0; g < 2; g++) {
            bf16x4 lo[8], hi[8];
#pragma unroll
            for (int q = 0; q < 8; q++)
                tr_read2(trb + (unsigned)((g * 8 + q) * 1024), lo[q], hi[q]);
            asm volatile("s_waitcnt lgkmcnt(0)" ::: "memory");
            __builtin_amdgcn_sched_barrier(0);
            __builtin_amdgcn_s_setprio(1);
#pragma unroll
            for (int q = 0; q < 8; q++) {
                bf16x8 af2;
#pragma unroll
                for (int t2 = 0; t2 < 4; t2++) { af2[t2] = lo[q][t2]; af2[t2 + 4] = hi[q][t2]; }
                oacc[0][g * 8 + q] = __builtin_amdgcn_mfma_f32_16x16x32_bf16(af2, bf2[0], oacc[0][g * 8 + q], 0, 0, 0);
                oacc[1][g * 8 + q] = __builtin_amdgcn_mfma_f32_16x16x32_bf16(af2, bf2[1], oacc[1][g * 8 + q], 0, 0, 0);
            }
            __builtin_amdgcn_s_setprio(0);
        }

        __syncthreads();
    }

#pragma unroll
    for (int rg = 0; rg < 2; rg++) {
        float li = 1.0f / lsum[rg];
        int hr = n0 + wv * 32 + rg * 16 + l15;
        if (hr >= NR) continue;
#pragma unroll
        for (int mm = 0; mm < 16; mm++) {
            short4 o;
            o.x = f2b(oacc[rg][mm][0] * li);
            o.y = f2b(oacc[rg][mm][1] * li);
            o.z = f2b(oacc[rg][mm][2] * li);
            o.w = f2b(oacc[rg][mm][3] * li);
            *(short4*)&C[(size_t)hr * 256 + mm * 16 + l4 * 4] = o;
        }
    }
}

// ---------------------------------------------------------------- CSR build (once per call)
__global__ void hist_kernel(const int* __restrict__ ei, int* __restrict__ deg)
{
    int e = blockIdx.x * 256 + threadIdx.x;
    if (e < E_EDGES) atomicAdd(&deg[ei[E_EDGES + e]], 1);
}

__global__ void scan1_kernel(const int* __restrict__ deg, int* __restrict__ incl,
                             int* __restrict__ bsum)
{
    __shared__ int s[256];
    int i = blockIdx.x * 256 + threadIdx.x;
    int v = (i < N_NODES) ? deg[i] : 0;
    s[threadIdx.x] = v;
    __syncthreads();
#pragma unroll
    for (int off = 1; off < 256; off <<= 1) {
        int t = (threadIdx.x >= off) ? s[threadIdx.x - off] : 0;
        __syncthreads();
        s[threadIdx.x] += t;
        __syncthreads();
    }
    if (i < N_NODES) incl[i] = s[threadIdx.x];
    if (threadIdx.x == 255) bsum[blockIdx.x] = s[255];
}

__global__ void scan2_kernel(int* __restrict__ bsum, int nb)
{
    __shared__ int s[256];
    int v = (threadIdx.x < nb) ? bsum[threadIdx.x] : 0;
    s[threadIdx.x] = v;
    __syncthreads();
#pragma unroll
    for (int off = 1; off < 256; off <<= 1) {
        int t = (threadIdx.x >= off) ? s[threadIdx.x - off] : 0;
        __syncthreads();
        s[threadIdx.x] += t;
        __syncthreads();
    }
    if (threadIdx.x < nb) bsum[threadIdx.x] = s[threadIdx.x];
}

__global__ void scan3_kernel(const int* __restrict__ deg, const int* __restrict__ incl,
                             const int* __restrict__ bsum, int* __restrict__ row_ptr,
                             int* __restrict__ cursor)
{
    int i = blockIdx.x * 256 + threadIdx.x;
    if (i >= N_NODES) return;
    int pref = (blockIdx.x > 0) ? bsum[blockIdx.x - 1] : 0;
    int start = pref + incl[i] - deg[i];
    row_ptr[i] = start;
    cursor[i]  = start;
    if (i == N_NODES - 1) row_ptr[N_NODES] = pref + incl[i];
}

__global__ void fill_kernel(const int* __restrict__ ei, const int* __restrict__ et,
                            int* __restrict__ cursor, int* __restrict__ eidx)
{
    int e = blockIdx.x * 256 + threadIdx.x;
    if (e >= E_EDGES) return;
    int tg = ei[E_EDGES + e];
    int slot = atomicAdd(&cursor[tg], 1);
    eidx[slot] = ei[e] | (et[e] << 16);   // src < 65536, type < 4
}

// ---------------------------------------------------------------- CSR gather of h into per-type buckets
__global__ void agg2_kernel(const int* __restrict__ row_ptr, const int* __restrict__ eidx,
                            const short* __restrict__ h, short* __restrict__ Bagg)
{
    int w = (blockIdx.x * 256 + threadIdx.x) >> 6;
    if (w >= N_NODES) return;
    int lane = threadIdx.x & 63;
    int s0 = row_ptr[w], s1 = row_ptr[w + 1];
    float a0[4] = {0, 0, 0, 0}, a1[4] = {0, 0, 0, 0}, a2[4] = {0, 0, 0, 0}, a3[4] = {0, 0, 0, 0};
    for (int i = s0; i < s1; i++) {
        int p = eidx[i];
        int s = p & 0xFFFF, t = p >> 16;   // t uniform across the wave
        short4 g = *(const short4*)&h[(size_t)s * EMB + lane * 4];
        float f0 = b2f(g.x), f1 = b2f(g.y), f2 = b2f(g.z), f3 = b2f(g.w);
        if (t == 0)      { a0[0] += f0; a0[1] += f1; a0[2] += f2; a0[3] += f3; }
        else if (t == 1) { a1[0] += f0; a1[1] += f1; a1[2] += f2; a1[3] += f3; }
        else if (t == 2) { a2[0] += f0; a2[1] += f1; a2[2] += f2; a2[3] += f3; }
        else             { a3[0] += f0; a3[1] += f1; a3[2] += f2; a3[3] += f3; }
    }
    short4 o;
    o.x = f2b(a0[0]); o.y = f2b(a0[1]); o.z = f2b(a0[2]); o.w = f2b(a0[3]);
    *(short4*)&Bagg[(size_t)w * 1024 + 0 * 256 + lane * 4] = o;
    o.x = f2b(a1[0]); o.y = f2b(a1[1]); o.z = f2b(a1[2]); o.w = f2b(a1[3]);
    *(short4*)&Bagg[(size_t)w * 1024 + 1 * 256 + lane * 4] = o;
    o.x = f2b(a2[0]); o.y = f2b(a2[1]); o.z = f2b(a2[2]); o.w = f2b(a2[3]);
    *(short4*)&Bagg[(size_t)w * 1024 + 2 * 256 + lane * 4] = o;
    o.x = f2b(a3[0]); o.y = f2b(a3[1]); o.z = f2b(a3[2]); o.w = f2b(a3[3]);
    *(short4*)&Bagg[(size_t)w * 1024 + 3 * 256 + lane * 4] = o;
}

// ---------------------------------------------------------------- fused node head
__global__ __launch_bounds__(512, 2) void head_kernel(
    const short* __restrict__ hmat, const short* __restrict__ WzT,
    const float* __restrict__ bz, float* __restrict__ out, int NR)
{
    __shared__ short hs[64 * 256];   // swizzled
    __shared__ float redm[64 * 8];
    __shared__ float reds[64 * 8];

    const int tid = threadIdx.x;
    const int lane = tid & 63, wv = tid >> 6;  // wv 0..7
    const int l4 = lane >> 4, l15 = lane & 15;
    const int n0 = blockIdx.x * 64;

#pragma unroll
    for (int i = 0; i < 4; i++) {
        int idx = tid + i * 512;
        int row = idx >> 5, kg = idx & 31;
        bf16x8 v = {0, 0, 0, 0, 0, 0, 0, 0};
        if (n0 + row < NR) v = *(const bf16x8*)&hmat[(size_t)(n0 + row) * 256 + kg * 8];
        *(bf16x8*)&hs[(row * 256 + kg * 8) ^ ((row & 7) << 3)] = v;
    }
    __syncthreads();

    f32x4 acc[4][4];
#pragma unroll
    for (int m = 0; m < 4; m++)
#pragma unroll
        for (int n = 0; n < 4; n++) acc[m][n] = (f32x4){0.f, 0.f, 0.f, 0.f};

#pragma unroll
    for (int kt = 0; kt < 256; kt += 32) {
        bf16x8 af[4], bfr[4];
#pragma unroll
        for (int m = 0; m < 4; m++) {
            int row = m * 16 + l15;
            af[m] = *(const bf16x8*)&hs[(row * 256 + kt + l4 * 8) ^ ((row & 7) << 3)];
        }
#pragma unroll
        for (int n = 0; n < 4; n++) {
            int col = wv * 64 + n * 16 + l15;
            bfr[n] = *(const bf16x8*)&WzT[(size_t)col * 256 + kt + l4 * 8];
        }
#pragma unroll
        for (int m = 0; m < 4; m++)
#pragma unroll
            for (int n = 0; n < 4; n++)
                acc[m][n] = __builtin_amdgcn_mfma_f32_16x16x32_bf16(af[m], bfr[n], acc[m][n], 0, 0, 0);
    }

    float bcol[4];
#pragma unroll
    for (int n = 0; n < 4; n++) bcol[n] = bz[wv * 64 + n * 16 + l15];
#pragma unroll
    for (int m = 0; m < 4; m++)
#pragma unroll
        for (int n = 0; n < 4; n++)
#pragma unroll
            for (int r = 0; r < 4; r++) acc[m][n][r] += bcol[n];

    float lg[4][4];
#pragma unroll
    for (int m = 0; m < 4; m++)
#pragma unroll
        for (int r = 0; r < 4; r++) {
            float v = fmaxf(fmaxf(acc[m][0][r], acc[m][1][r]), fmaxf(acc[m][2][r], acc[m][3][r]));
            v = fmaxf(v, __shfl_xor(v, 1));
            v = fmaxf(v, __shfl_xor(v, 2));
            v = fmaxf(v, __shfl_xor(v, 4));
            v = fmaxf(v, __shfl_xor(v, 8));
            if (l15 == 0) redm[(m * 16 + l4 * 4 + r) * 8 + wv] = v;
        }
    __syncthreads();
#pragma unroll
    for (int m = 0; m < 4; m++)
#pragma unroll
        for (int r = 0; r < 4; r++) {
            int row = m * 16 + l4 * 4 + r;
            float v = redm[row * 8 + 0];
#pragma unroll
            for (int w = 1; w < 8; w++) v = fmaxf(v, redm[row * 8 + w]);
            lg[m][r] = v;
        }
#pragma unroll
    for (int m = 0; m < 4; m++)
#pragma unroll
        for (int r = 0; r < 4; r++) {
            float gm = lg[m][r];
            float s = __expf(acc[m][0][r] - gm) + __expf(acc[m][1][r] - gm)
                    + __expf(acc[m][2][r] - gm) + __expf(acc[m][3][r] - gm);
            s += __shfl_xor(s, 1);
            s += __shfl_xor(s, 2);
            s += __shfl_xor(s, 4);
            s += __shfl_xor(s, 8);
            if (l15 == 0) reds[(m * 16 + l4 * 4 + r) * 8 + wv] = s;
        }
    __syncthreads();
#pragma unroll
    for (int m = 0; m < 4; m++)
#pragma unroll
        for (int r = 0; r < 4; r++) {
            int row = m * 16 + l4 * 4 + r;
            float s = reds[row * 8 + 0];
#pragma unroll
            for (int w = 1; w < 8; w++) s += reds[row * 8 + w];
            lg[m][r] += __logf(s);
        }
#pragma unroll
    for (int m = 0; m < 4; m++)
#pragma unroll
        for (int r = 0; r < 4; r++) {
            int hr = n0 + m * 16 + l4 * 4 + r;
            if (hr >= NR) continue;
#pragma unroll
            for (int n = 0; n < 4; n++)
                out[(size_t)hr * VOCABSZ + wv * 64 + n * 16 + l15] = acc[m][n][r] - lg[m][r];
        }
}

// ---------------------------------------------------------------- node projections for edge head
__global__ __launch_bounds__(256) void nodeproj_kernel(
    const short* __restrict__ h, const float* __restrict__ Wg,
    float* __restrict__ eproj)
{
    int lane = threadIdx.x & 63;
    int gw   = (blockIdx.x * 256 + threadIdx.x) >> 6;
    int nw   = (gridDim.x * 256) >> 6;
    float ws[4][5], wt[4][5];
#pragma unroll
    for (int c = 0; c < 4; c++)
#pragma unroll
        for (int j = 0; j < 5; j++) {
            ws[c][j] = Wg[(size_t)(lane * 4 + c) * 5 + j];
            wt[c][j] = Wg[(size_t)(256 + lane * 4 + c) * 5 + j];
        }

    for (int n = gw; n < N_NODES; n += nw) {
        short4 hv = *(const short4*)&h[(size_t)n * EMB + lane * 4];
        float f[4] = { b2f(hv.x), b2f(hv.y), b2f(hv.z), b2f(hv.w) };
        float a[5] = {0, 0, 0, 0, 0}, b[5] = {0, 0, 0, 0, 0};
#pragma unroll
        for (int c = 0; c < 4; c++)
#pragma unroll
            for (int j = 0; j < 5; j++) {
                a[j] += f[c] * ws[c][j];
                b[j] += f[c] * wt[c][j];
            }
#pragma unroll
        for (int j = 0; j < 5; j++)
#pragma unroll
            for (int off = 32; off; off >>= 1) {
                a[j] += __shfl_xor(a[j], off);
                b[j] += __shfl_xor(b[j], off);
            }
        if (lane == 0) {
#pragma unroll
            for (int j = 0; j < 5; j++) {
                eproj[(size_t)n * 10 + j]     = a[j];
                eproj[(size_t)n * 10 + 5 + j] = b[j];
            }
        }
    }
}

// ---------------------------------------------------------------- edge head combine
__global__ void edge_lsm_kernel(const int* __restrict__ ei,
                                const float* __restrict__ eproj,
                                const float* __restrict__ bg,
                                float* __restrict__ out)
{
    int e = blockIdx.x * 256 + threadIdx.x;
    if (e >= E_EDGES) return;
    int s = ei[e], t = ei[E_EDGES + e];
    const float* ps = &eproj[(size_t)s * 10];
    const float* pt = &eproj[(size_t)t * 10 + 5];
    float z[5];
#pragma unroll
    for (int j = 0; j < 5; j++) z[j] = ps[j] + pt[j] + bg[j];
    float mm = fmaxf(fmaxf(fmaxf(z[0], z[1]), fmaxf(z[2], z[3])), z[4]);
    float ss = __expf(z[0] - mm) + __expf(z[1] - mm) + __expf(z[2] - mm)
             + __expf(z[3] - mm) + __expf(z[4] - mm);
    float lg = mm + __logf(ss);
    float* o = &out[(size_t)e * 5];
#pragma unroll
    for (int j = 0; j < 5; j++) o[j] = z[j] - lg;
}

// ---------------------------------------------------------------- launch
extern "C" void kernel_launch(void* const* d_in, const int* in_sizes, int n_in,
                              void* d_out, int out_size, void* d_ws, size_t ws_size,
                              hipStream_t stream)
{
    const int*   tgt_x = (const int*)  d_in[0];
    const float* x     = (const float*)d_in[1];
    const int*   ei    = (const int*)  d_in[2];
    const int*   et    = (const int*)  d_in[3];
    const float* table = (const float*)d_in[4];
    const float* Wh1   = (const float*)d_in[5];
    const float* Wrel1 = (const float*)d_in[6];
    const float* Wsrc1 = (const float*)d_in[7];
    const float* Wh3   = (const float*)d_in[8];
    const float* Wrel3 = (const float*)d_in[9];
    const float* Wsrc3 = (const float*)d_in[10];
    const float* Wz    = (const float*)d_in[11];
    const float* bz    = (const float*)d_in[12];
    const float* Wg    = (const float*)d_in[13];
    const float* bg    = (const float*)d_in[14];
    float* out = (float*)d_out;

    // ---- workspace layout
    short* h_a = (short*)d_ws;                              // N*256 bf16
    short* h_b = h_a + (size_t)N_NODES * EMB;
    short* C   = h_b + (size_t)N_NODES * EMB;               // N*256 bf16 (ctx)
    short* Bagg = C + (size_t)N_NODES * EMB;                // N*1024 bf16
    short* k1b = Bagg + (size_t)N_NODES * 1024;             // [1024][256]
    short* k3b = k1b + M_SRC * EMB;
    short* x_b = k3b + M_SRC * EMB;                         // [1024][512]
    short* WsT1 = x_b + M_SRC * HIDN;                       // [256][512]
    short* WsT3 = WsT1 + EMB * HIDN;
    short* Wcat1 = WsT3 + EMB * HIDN;                       // [256][1280]
    short* Wcat3 = Wcat1 + EMB * KW;
    short* WzT  = Wcat3 + EMB * KW;                         // [512][256]
    int* deg     = (int*)(WzT + VOCABSZ * EMB);             // N
    int* incl    = deg + N_NODES;                           // N
    int* bsum    = incl + N_NODES;                          // 256
    int* row_ptr = bsum + 256;                              // N+1
    int* cursor  = row_ptr + N_NODES + 1;                   // N
    int* eidx    = cursor + N_NODES;                        // E
    float* eproj = (float*)(eidx + E_EDGES);                // N*10 f32

    const int gN64 = (N_NODES + 63) / 64;                   // 782
    const int nb1 = (N_NODES + 255) / 256;                  // 196

    // ---- CSR build (edges constant across layers)
    hipMemsetAsync(deg, 0, N_NODES * sizeof(int), stream);
    hist_kernel<<<(E_EDGES + 255) / 256, 256, 0, stream>>>(ei, deg);
    scan1_kernel<<<nb1, 256, 0, stream>>>(deg, incl, bsum);
    scan2_kernel<<<1, 256, 0, stream>>>(bsum, nb1);
    scan3_kernel<<<nb1, 256, 0, stream>>>(deg, incl, bsum, row_ptr, cursor);
    fill_kernel<<<(E_EDGES + 255) / 256, 256, 0, stream>>>(ei, et, cursor, eidx);

    // ---- weight prep
    convert_kernel<<<(M_SRC * HIDN / 4 + 255) / 256, 256, 0, stream>>>(x, x_b, M_SRC * HIDN);
    transpose_kernel<float><<<dim3(EMB / 32, HIDN / 32), 256, 0, stream>>>(Wsrc1, WsT1, HIDN, EMB);
    transpose_kernel<float><<<dim3(EMB / 32, HIDN / 32), 256, 0, stream>>>(Wsrc3, WsT3, HIDN, EMB);
    transposeW_kernel<<<dim3(8, 8, 10), 256, 0, stream>>>(Wh1, Wh3, Wrel1, Wrel3, Wcat1, Wcat3);
    transpose_kernel<float><<<dim3(VOCABSZ / 32, EMB / 32), 256, 0, stream>>>(Wz, WzT, EMB, VOCABSZ);

    // ---- k = x @ Wsrc (bf16)
    mgemm<0><<<dim3(M_SRC / 128, EMB / 128), 256, 0, stream>>>(x_b, WsT1, k1b, nullptr, nullptr, M_SRC, HIDN, EMB);
    mgemm<0><<<dim3(M_SRC / 128, EMB / 128), 256, 0, stream>>>(x_b, WsT3, k3b, nullptr, nullptr, M_SRC, HIDN, EMB);

    // ---- embedding
    embed_kernel<<<N_NODES, 256, 0, stream>>>(tgt_x, table, h_a);

    short* h_cur = h_a;
    short* h_nxt = h_b;
    for (int layer = 0; layer < 3; layer++) {
        const short* kb   = (layer < 2) ? k1b   : k3b;
        const short* Wcat = (layer < 2) ? Wcat1 : Wcat3;

        // C = softmax(h k^T / 16) @ k   (fused flash, 32 rows/wave, bf16 out)
        attn_flash<<<gN64, 128, 0, stream>>>(h_cur, kb, C, N_NODES);
        // Bagg[tgt] = per-type sums of h[src]
        agg2_kernel<<<(N_NODES + 3) / 4, 256, 0, stream>>>(row_ptr, eidx, h_cur, Bagg);
        // h_nxt = relu([h|Bagg] @ Wcat^T + C)   — single-pass A, pipelined v4
        mgemm_wide<<<dim3(gN64, 1), 256, 0, stream>>>(h_cur, Bagg, Wcat, h_nxt, C, N_NODES);
        short* tmp = h_cur; h_cur = h_nxt; h_nxt = tmp;
    }

    // ---- node head (fused GEMM + log-softmax)
    head_kernel<<<gN64, 512, 0, stream>>>(h_cur, WzT, bz, out, N_NODES);

    // ---- edge head: node projections + per-edge combine
    nodeproj_kernel<<<2048, 256, 0, stream>>>(h_cur, Wg, eproj);
    edge_lsm_kernel<<<(E_EDGES + 255) / 256, 256, 0, stream>>>(ei, eproj, bg,
                                                               out + (size_t)N_NODES * VOCABSZ);
}